// Round 1
// baseline (9373.618 us; speedup 1.0000x reference)
//
#include <hip/hip_runtime.h>
#include <cmath>

// LSS pipeline, fp32 reference-faithful implementation.
// Workspace budget: ~63.7 MB of floats (see layout in kernel_launch).

__device__ __forceinline__ float sigf(float x){ return 1.0f/(1.0f+expf(-x)); }
__device__ __forceinline__ float siluf(float x){ return x*sigf(x); }

// ---------- K1: 1x1 conv 1280->256 + BN + SiLU ----------
// grid (2, 32, 12) block 256; each thread computes 8 consecutive co for one pixel
__global__ __launch_bounds__(256) void k_conv1(
    const float* __restrict__ feats, const float* __restrict__ W,
    const float* __restrict__ bns, const float* __restrict__ bnb,
    float* __restrict__ out)
{
  int p = blockIdx.x*256 + threadIdx.x;
  int cog = blockIdx.y; int n = blockIdx.z;
  if (p >= 396) return;
  float acc[8];
  #pragma unroll
  for (int j=0;j<8;++j) acc[j]=0.f;
  const float* f = feats + (size_t)n*1280*396 + p;
  const float* w = W + (size_t)cog*8*1280;
  for (int ci=0; ci<1280; ++ci){
    float fv = f[(size_t)ci*396];
    #pragma unroll
    for (int j=0;j<8;++j) acc[j] += fv * w[j*1280+ci];
  }
  #pragma unroll
  for (int j=0;j<8;++j){
    int co = cog*8+j;
    float v = acc[j]*bns[co]+bnb[co];
    out[((size_t)n*256+co)*396 + p] = siluf(v);
  }
}

// ---------- row mean (for SE): one block per row ----------
__global__ __launch_bounds__(256) void k_rowmean(
    const float* __restrict__ in, float* __restrict__ out, int rowlen, float inv)
{
  __shared__ float ws[4];
  int row = blockIdx.x; int t = threadIdx.x;
  const float* p = in + (size_t)row*rowlen;
  float s = 0.f;
  for (int i=t; i<rowlen; i+=256) s += p[i];
  #pragma unroll
  for (int off=32; off; off>>=1) s += __shfl_down(s, off);
  if ((t&63)==0) ws[t>>6] = s;
  __syncthreads();
  if (t==0) out[row] = (ws[0]+ws[1]+ws[2]+ws[3]) * inv;
}

// ---------- SE FC: g = sigmoid(silu(m@w1.T+b1)@w2.T+b2), C=256, H<=32 ----------
__global__ __launch_bounds__(256) void k_se_fc(
    const float* __restrict__ mean, const float* __restrict__ w1, const float* __restrict__ b1,
    const float* __restrict__ w2, const float* __restrict__ b2, float* __restrict__ g, int H)
{
  __shared__ float m[256];
  __shared__ float h[32];
  int n = blockIdx.x; int t = threadIdx.x;
  m[t] = mean[n*256 + t];
  __syncthreads();
  if (t < H){
    float s = b1[t];
    for (int c=0; c<256; ++c) s += m[c]*w1[t*256+c];
    h[t] = siluf(s);
  }
  __syncthreads();
  float s = b2[t];
  for (int j=0; j<H; ++j) s += h[j]*w2[t*H+j];
  g[n*256+t] = sigf(s);
}

// ---------- scale rows by g ----------
__global__ __launch_bounds__(256) void k_scale(
    float* __restrict__ x, const float* __restrict__ g, int rowlen, int total)
{
  int i = blockIdx.x*256 + threadIdx.x;
  if (i < total){ int row = i / rowlen; x[i] *= g[row]; }
}

// ---------- K3: 3x3 conv 256->256 on 12x33, pad 1, BN+SiLU ----------
// grid (co=256, n=12), block 256; each thread handles pixel t and t+256
__global__ __launch_bounds__(256) void k_conv3_small(
    const float* __restrict__ in, const float* __restrict__ W,
    const float* __restrict__ bns, const float* __restrict__ bnb,
    float* __restrict__ out)
{
  __shared__ float tile[14*35];   // padded 12x33 -> 14x35
  __shared__ float wk[9];
  int co = blockIdx.x, n = blockIdx.y, t = threadIdx.x;
  int p1 = t + 256;
  int y0 = t/33, x0 = t%33;
  int base0 = y0*35 + x0;
  int base1 = 0;
  if (p1 < 396) base1 = (p1/33)*35 + (p1%33);
  float a0=0.f, a1=0.f;
  const float* inb = in + (size_t)n*256*396;
  const float* wb  = W + (size_t)co*2304;
  for (int ci=0; ci<256; ++ci){
    __syncthreads();
    if (t < 9) wk[t] = wb[ci*9 + t];
    for (int i=t; i<490; i+=256){
      int yy = i/35, xx = i%35;
      float v = 0.f;
      if (yy>=1 && yy<=12 && xx>=1 && xx<=33) v = inb[(size_t)ci*396 + (yy-1)*33 + (xx-1)];
      tile[i] = v;
    }
    __syncthreads();
    #pragma unroll
    for (int dy=0; dy<3; ++dy)
      #pragma unroll
      for (int dx=0; dx<3; ++dx){
        float w = wk[dy*3+dx];
        a0 += w * tile[base0 + dy*35 + dx];
        a1 += w * tile[base1 + dy*35 + dx];
      }
  }
  out[((size_t)n*256+co)*396 + t] = siluf(a0*bns[co]+bnb[co]);
  if (p1 < 396)
    out[((size_t)n*256+co)*396 + p1] = siluf(a1*bns[co]+bnb[co]);
}

// ---------- heads: depth logits (40) and ctx (64), 1x1 convs ----------
// grid (2, 104, 12) block 256
__global__ __launch_bounds__(256) void k_heads(
    const float* __restrict__ x, const float* __restrict__ dhw, const float* __restrict__ dhb,
    const float* __restrict__ chw, const float* __restrict__ chb,
    float* __restrict__ dep, float* __restrict__ ctx)
{
  int p = blockIdx.x*256 + threadIdx.x;
  int co = blockIdx.y; int n = blockIdx.z;
  if (p >= 396) return;
  const float* xb = x + (size_t)n*256*396 + p;
  const float* w = (co < 40) ? (dhw + (size_t)co*256) : (chw + (size_t)(co-40)*256);
  float acc = 0.f;
  for (int ci=0; ci<256; ++ci) acc += xb[(size_t)ci*396] * w[ci];
  if (co < 40) dep[((size_t)n*40+co)*396 + p] = acc + dhb[co];
  else { int c = co-40; ctx[((size_t)n*64+c)*396 + p] = acc + chb[c]; }
}

// ---------- softmax over 40 depth channels, per pixel ----------
__global__ __launch_bounds__(256) void k_softmax40(float* __restrict__ dep)
{
  int i = blockIdx.x*256 + threadIdx.x;
  if (i >= 12*396) return;
  int n = i/396, p = i%396;
  float* base = dep + (size_t)n*40*396 + p;
  float mx = -1e30f;
  for (int d=0; d<40; ++d) mx = fmaxf(mx, base[(size_t)d*396]);
  float s = 0.f;
  for (int d=0; d<40; ++d){ float e = expf(base[(size_t)d*396]-mx); base[(size_t)d*396]=e; s+=e; }
  float inv = 1.f/s;
  for (int d=0; d<40; ++d) base[(size_t)d*396] *= inv;
}

// ---------- geometry: per frustum point -> voxel offset (z*640000+ix*100+iy) or -1 ----------
__global__ __launch_bounds__(256) void k_geom(
    const float* __restrict__ rots, const float* __restrict__ trans,
    const float* __restrict__ intr, int* __restrict__ vox)
{
  int pt = blockIdx.x*256 + threadIdx.x;
  if (pt >= 190080) return;
  int b = pt/95040; int r = pt%95040;
  int n = r/15840;  int r2 = r%15840;
  int d = r2/396;   int pim = r2%396;
  int y = pim/33, x = pim%33;
  int bn = b*6+n;
  const float* R = rots + (size_t)bn*9;
  const float* T = trans + (size_t)bn*3;
  const float* K = intr + (size_t)bn*9;
  float fx=K[0], cx=K[2], fy=K[4], cy=K[5];
  float xs = (float)x * 32.96875f;                    // 1055/32 exact
  float ys = (float)((double)y * (383.0/11.0));
  float dv = 4.0f + (float)d;
  float camx = (xs-cx)*dv/fx;
  float camy = (ys-cy)*dv/fy;
  float gx = R[0]*camx + R[1]*camy + R[2]*dv + T[0];
  float gy = R[3]*camx + R[4]*camy + R[5]*dv + T[1];
  float gz = R[6]*camx + R[7]*camy + R[8]*dv + T[2];
  int ix = (int)floorf(gx + 50.f);
  int iy = (int)floorf(gy + 50.f);
  int iz = (int)floorf((gz + 10.f)/5.f);
  bool valid = (ix>=0 && ix<100 && iy>=0 && iy<100 && iz>=0 && iz<4);
  vox[pt] = valid ? (iz*640000 + ix*100 + iy) : -1;
}

__global__ __launch_bounds__(256) void k_zero(float* __restrict__ p, int n)
{
  int i = blockIdx.x*256 + threadIdx.x;
  if (i < n) p[i] = 0.f;
}

// ---------- splat: bev[b, z*64+c, ix, iy] += ctx*depth ----------
// grid (743, 64) block 256; blockIdx.y = c
__global__ __launch_bounds__(256) void k_splat(
    const int* __restrict__ vox, const float* __restrict__ ctx,
    const float* __restrict__ dep, float* __restrict__ bev)
{
  int pt = blockIdx.x*256 + threadIdx.x;
  int c = blockIdx.y;
  if (pt >= 190080) return;
  int v = vox[pt];
  if (v < 0) return;
  int b = pt/95040; int r = pt%95040;
  int n = r/15840;  int r2 = r%15840;
  int dd = r2/396;  int pim = r2%396;
  int bn = b*6+n;
  float val = ctx[((size_t)bn*64+c)*396 + pim] * dep[((size_t)bn*40+dd)*396 + pim];
  atomicAdd(&bev[(size_t)b*2560000 + (size_t)c*10000 + v], val);
}

// ---------- BEV 3x3 conv (Cin=256), BN + ReLU (+ optional residual) ----------
// grid (49, Cout, 2) block 256; 16x16 output tile
__global__ __launch_bounds__(256) void k_conv3_bev(
    const float* __restrict__ in, const float* __restrict__ W,
    const float* __restrict__ bns, const float* __restrict__ bnb,
    const float* __restrict__ res, float* __restrict__ out)
{
  __shared__ float wsl[2304];
  __shared__ float tile[18*18];
  int co = blockIdx.y, b = blockIdx.z, tid = threadIdx.x;
  int Cout = gridDim.y;
  int ty = (blockIdx.x/7)*16, tx = (blockIdx.x%7)*16;
  int ly = tid/16, lx = tid%16;
  int oy = ty+ly, ox = tx+lx;
  const float* wb = W + (size_t)co*2304;
  for (int i=tid; i<2304; i+=256) wsl[i] = wb[i];
  const float* inb = in + (size_t)b*256*10000;
  float acc = 0.f;
  for (int ci=0; ci<256; ++ci){
    __syncthreads();
    for (int i=tid; i<324; i+=256){
      int yy = ty-1 + i/18, xx = tx-1 + i%18;
      float v = 0.f;
      if (yy>=0 && yy<100 && xx>=0 && xx<100) v = inb[(size_t)ci*10000 + yy*100 + xx];
      tile[i] = v;
    }
    __syncthreads();
    const float* wk = wsl + ci*9;
    int base = ly*18 + lx;
    acc += wk[0]*tile[base]    + wk[1]*tile[base+1]  + wk[2]*tile[base+2]
         + wk[3]*tile[base+18] + wk[4]*tile[base+19] + wk[5]*tile[base+20]
         + wk[6]*tile[base+36] + wk[7]*tile[base+37] + wk[8]*tile[base+38];
  }
  if (oy<100 && ox<100){
    float v = acc*bns[co] + bnb[co];
    v = fmaxf(v, 0.f);
    size_t o = ((size_t)(b*Cout+co))*10000 + oy*100 + ox;
    if (res) v += res[o];
    out[o] = v;
  }
}

// ---------- final 1x1 conv 128->16 + bias -> d_out ----------
// grid (40, 16, 2) block 256
__global__ __launch_bounds__(256) void k_final(
    const float* __restrict__ h, const float* __restrict__ W, const float* __restrict__ bias,
    float* __restrict__ out)
{
  int pix = blockIdx.x*256 + threadIdx.x;
  int oc = blockIdx.y, b = blockIdx.z;
  if (pix >= 10000) return;
  const float* hb = h + (size_t)b*128*10000 + pix;
  const float* w = W + (size_t)oc*128;
  float acc = bias[oc];
  for (int ci=0; ci<128; ++ci) acc += hb[(size_t)ci*10000]*w[ci];
  out[((size_t)(b*16+oc))*10000 + pix] = acc;
}

extern "C" void kernel_launch(void* const* d_in, const int* in_sizes, int n_in,
                              void* d_out, int out_size, void* d_ws, size_t ws_size,
                              hipStream_t stream)
{
  (void)in_sizes; (void)n_in; (void)out_size; (void)ws_size;
  const float* feats = (const float*)d_in[0];
  const float* rots  = (const float*)d_in[1];
  const float* trans = (const float*)d_in[2];
  const float* intr  = (const float*)d_in[3];
  const float* nw1   = (const float*)d_in[4];
  const float* bn1s  = (const float*)d_in[5];
  const float* bn1b  = (const float*)d_in[6];
  const float* se1w1 = (const float*)d_in[7];
  const float* se1b1 = (const float*)d_in[8];
  const float* se1w2 = (const float*)d_in[9];
  const float* se1b2 = (const float*)d_in[10];
  const float* nw2   = (const float*)d_in[11];
  const float* bn2s  = (const float*)d_in[12];
  const float* bn2b  = (const float*)d_in[13];
  const float* dhw   = (const float*)d_in[14];
  const float* dhb   = (const float*)d_in[15];
  const float* chw   = (const float*)d_in[16];
  const float* chb   = (const float*)d_in[17];
  const float* bcw1  = (const float*)d_in[18];
  const float* bcs1  = (const float*)d_in[19];
  const float* bcb1  = (const float*)d_in[20];
  const float* bcsw1 = (const float*)d_in[21];
  const float* bcsb1 = (const float*)d_in[22];
  const float* bcsw2 = (const float*)d_in[23];
  const float* bcsb2 = (const float*)d_in[24];
  const float* bcw2  = (const float*)d_in[25];
  const float* bcs2  = (const float*)d_in[26];
  const float* bcb2  = (const float*)d_in[27];
  const float* dw1   = (const float*)d_in[28];
  const float* ds1   = (const float*)d_in[29];
  const float* db1   = (const float*)d_in[30];
  const float* dw2   = (const float*)d_in[31];
  const float* db2   = (const float*)d_in[32];
  float* out = (float*)d_out;

  // workspace layout (floats)
  float* ws    = (float*)d_ws;
  float* x1    = ws;                    // 12*256*396 = 1216512
  float* x2    = x1 + 1216512;          // 1216512
  float* dep   = x2 + 1216512;          // 12*40*396 = 190080
  float* ctx   = dep + 190080;          // 12*64*396 = 304128
  float* mean1 = ctx + 304128;          // 3072
  float* g1    = mean1 + 3072;          // 3072
  int*   vox   = (int*)(g1 + 3072);     // 190080 ints
  float* bev   = (float*)(vox + 190080);// 2*256*10000 = 5120000
  float* h1    = bev + 5120000;         // 5120000
  float* mean2 = h1 + 5120000;          // 512
  float* g2    = mean2 + 512;           // 512
  float* h3    = g2 + 512;              // 2*128*10000 = 2560000
  // total: 15,924,480 floats = 63.7 MB

  // image branch
  k_conv1<<<dim3(2,32,12),256,0,stream>>>(feats,nw1,bn1s,bn1b,x1);
  k_rowmean<<<3072,256,0,stream>>>(x1,mean1,396,1.f/396.f);
  k_se_fc<<<12,256,0,stream>>>(mean1,se1w1,se1b1,se1w2,se1b2,g1,32);
  k_scale<<<(1216512+255)/256,256,0,stream>>>(x1,g1,396,1216512);
  k_conv3_small<<<dim3(256,12),256,0,stream>>>(x1,nw2,bn2s,bn2b,x2);
  k_heads<<<dim3(2,104,12),256,0,stream>>>(x2,dhw,dhb,chw,chb,dep,ctx);
  k_softmax40<<<(4752+255)/256,256,0,stream>>>(dep);

  // lift-splat
  k_geom<<<(190080+255)/256,256,0,stream>>>(rots,trans,intr,vox);
  k_zero<<<(5120000+255)/256,256,0,stream>>>(bev,5120000);
  k_splat<<<dim3(743,64),256,0,stream>>>(vox,ctx,dep,bev);

  // BEV encoder
  k_conv3_bev<<<dim3(49,256,2),256,0,stream>>>(bev,bcw1,bcs1,bcb1,nullptr,h1);
  k_rowmean<<<512,256,0,stream>>>(h1,mean2,10000,1e-4f);
  k_se_fc<<<2,256,0,stream>>>(mean2,bcsw1,bcsb1,bcsw2,bcsb2,g2,16);
  k_scale<<<(5120000+255)/256,256,0,stream>>>(h1,g2,10000,5120000);
  k_conv3_bev<<<dim3(49,256,2),256,0,stream>>>(h1,bcw2,bcs2,bcb2,bev,bev);   // bev += relu(bn(conv(h1)))
  k_conv3_bev<<<dim3(49,128,2),256,0,stream>>>(bev,dw1,ds1,db1,nullptr,h3);
  k_final<<<dim3(40,16,2),256,0,stream>>>(h3,dw2,db2,out);
}

// Round 2
// 2419.242 us; speedup vs baseline: 3.8746x; 3.8746x over previous
//
#include <hip/hip_runtime.h>
#include <cmath>

// LSS pipeline. R1: co-blocked BEV/image 3x3 convs with transposed weights.

__device__ __forceinline__ float sigf(float x){ return 1.0f/(1.0f+expf(-x)); }
__device__ __forceinline__ float siluf(float x){ return x*sigf(x); }

// ---------- K1: 1x1 conv 1280->256 + BN + SiLU ----------
__global__ __launch_bounds__(256) void k_conv1(
    const float* __restrict__ feats, const float* __restrict__ W,
    const float* __restrict__ bns, const float* __restrict__ bnb,
    float* __restrict__ out)
{
  int p = blockIdx.x*256 + threadIdx.x;
  int cog = blockIdx.y; int n = blockIdx.z;
  if (p >= 396) return;
  float acc[8];
  #pragma unroll
  for (int j=0;j<8;++j) acc[j]=0.f;
  const float* f = feats + (size_t)n*1280*396 + p;
  const float* w = W + (size_t)cog*8*1280;
  for (int ci=0; ci<1280; ++ci){
    float fv = f[(size_t)ci*396];
    #pragma unroll
    for (int j=0;j<8;++j) acc[j] += fv * w[j*1280+ci];
  }
  #pragma unroll
  for (int j=0;j<8;++j){
    int co = cog*8+j;
    float v = acc[j]*bns[co]+bnb[co];
    out[((size_t)n*256+co)*396 + p] = siluf(v);
  }
}

// ---------- row mean ----------
__global__ __launch_bounds__(256) void k_rowmean(
    const float* __restrict__ in, float* __restrict__ out, int rowlen, float inv)
{
  __shared__ float ws[4];
  int row = blockIdx.x; int t = threadIdx.x;
  const float* p = in + (size_t)row*rowlen;
  float s = 0.f;
  for (int i=t; i<rowlen; i+=256) s += p[i];
  #pragma unroll
  for (int off=32; off; off>>=1) s += __shfl_down(s, off);
  if ((t&63)==0) ws[t>>6] = s;
  __syncthreads();
  if (t==0) out[row] = (ws[0]+ws[1]+ws[2]+ws[3]) * inv;
}

// ---------- SE FC ----------
__global__ __launch_bounds__(256) void k_se_fc(
    const float* __restrict__ mean, const float* __restrict__ w1, const float* __restrict__ b1,
    const float* __restrict__ w2, const float* __restrict__ b2, float* __restrict__ g, int H)
{
  __shared__ float m[256];
  __shared__ float h[32];
  int n = blockIdx.x; int t = threadIdx.x;
  m[t] = mean[n*256 + t];
  __syncthreads();
  if (t < H){
    float s = b1[t];
    for (int c=0; c<256; ++c) s += m[c]*w1[t*256+c];
    h[t] = siluf(s);
  }
  __syncthreads();
  float s = b2[t];
  for (int j=0; j<H; ++j) s += h[j]*w2[t*H+j];
  g[n*256+t] = sigf(s);
}

// ---------- scale rows by g ----------
__global__ __launch_bounds__(256) void k_scale(
    float* __restrict__ x, const float* __restrict__ g, int rowlen, int total)
{
  int i = blockIdx.x*256 + threadIdx.x;
  if (i < total){ int row = i / rowlen; x[i] *= g[row]; }
}

// ---------- weight transpose: W[co][ci][tap] -> Wt[ci*9+tap][co] ----------
__global__ __launch_bounds__(256) void k_wtrans(
    const float* __restrict__ W, float* __restrict__ Wt, int Cout)
{
  int i = blockIdx.x*256 + threadIdx.x;
  int total = Cout*2304;
  if (i >= total) return;
  int co = i / 2304;
  int r  = i % 2304;     // ci*9+tap
  Wt[(size_t)r*Cout + co] = W[i];
}

// ---------- 3x3 conv on 12x33, co-blocked (8 co/block), BN+SiLU ----------
// grid (32, 12); block 256. Thread: cq=tid>>7 (2 co-quads), pos=tid&127 (108 active)
// pos -> y=pos/9, xq=pos%9; outputs (y, xq*4..xq*4+3) x 4 co.
__global__ __launch_bounds__(256) void k_conv3_small2(
    const float* __restrict__ in, const float* __restrict__ Wt,
    const float* __restrict__ bns, const float* __restrict__ bnb,
    float* __restrict__ out)
{
  const int CI_CHUNK = 8;
  __shared__ __align__(16) float sw[8*72];    // [ci][tap][8co]
  __shared__ __align__(16) float st[8*532];   // [ci][14*38] padded tile
  int tid = threadIdx.x;
  int cog = blockIdx.x, n = blockIdx.y;
  int cq = tid >> 7;          // 0..1
  int pos = tid & 127;        // 0..127, active < 108
  int y = pos / 9, xq = pos % 9;
  int x0 = xq * 4;
  bool active = pos < 108;
  float acc[4][4];
  #pragma unroll
  for (int p=0;p<4;++p)
    #pragma unroll
    for (int j=0;j<4;++j) acc[p][j]=0.f;
  const float* inb = in + (size_t)n*256*396;
  for (int c0=0; c0<256; c0+=CI_CHUNK){
    __syncthreads();
    for (int i=tid; i<CI_CHUNK*72; i+=256){
      int ci = i/72, r = i%72;
      int tap = r/8, j = r%8;
      sw[i] = Wt[((size_t)(c0+ci)*9 + tap)*256 + cog*8 + j];
    }
    for (int i=tid; i<CI_CHUNK*532; i+=256){
      int ci = i/532, r = i%532;
      int yy = r/38 - 1, xx = r%38 - 1;
      float v = 0.f;
      if (yy>=0 && yy<12 && xx>=0 && xx<33) v = inb[(size_t)(c0+ci)*396 + yy*33 + xx];
      st[i] = v;
    }
    __syncthreads();
    if (active){
      #pragma unroll 2
      for (int ci=0; ci<CI_CHUNK; ++ci){
        const float* tt = st + ci*532 + y*38 + x0;
        const float* tw = sw + ci*72 + cq*4;
        float tv[3][6];
        #pragma unroll
        for (int r=0;r<3;++r)
          #pragma unroll
          for (int i2=0;i2<6;++i2) tv[r][i2] = tt[r*38+i2];
        #pragma unroll
        for (int r=0;r<3;++r)
          #pragma unroll
          for (int s=0;s<3;++s){
            float4 wv = *(const float4*)(tw + (r*3+s)*8);
            #pragma unroll
            for (int p=0;p<4;++p){
              float t = tv[r][p+s];
              acc[p][0] += wv.x*t; acc[p][1] += wv.y*t;
              acc[p][2] += wv.z*t; acc[p][3] += wv.w*t;
            }
          }
      }
    }
  }
  if (active){
    #pragma unroll
    for (int j=0;j<4;++j){
      int co = cog*8 + cq*4 + j;
      float s = bns[co], bb = bnb[co];
      size_t base = ((size_t)n*256+co)*396 + y*33;
      #pragma unroll
      for (int p=0;p<4;++p){
        int ox = x0+p;
        if (ox < 33) out[base+ox] = siluf(acc[p][j]*s+bb);
      }
    }
  }
}

// ---------- heads ----------
__global__ __launch_bounds__(256) void k_heads(
    const float* __restrict__ x, const float* __restrict__ dhw, const float* __restrict__ dhb,
    const float* __restrict__ chw, const float* __restrict__ chb,
    float* __restrict__ dep, float* __restrict__ ctx)
{
  int p = blockIdx.x*256 + threadIdx.x;
  int co = blockIdx.y; int n = blockIdx.z;
  if (p >= 396) return;
  const float* xb = x + (size_t)n*256*396 + p;
  const float* w = (co < 40) ? (dhw + (size_t)co*256) : (chw + (size_t)(co-40)*256);
  float acc = 0.f;
  for (int ci=0; ci<256; ++ci) acc += xb[(size_t)ci*396] * w[ci];
  if (co < 40) dep[((size_t)n*40+co)*396 + p] = acc + dhb[co];
  else { int c = co-40; ctx[((size_t)n*64+c)*396 + p] = acc + chb[c]; }
}

// ---------- softmax over 40 depth channels ----------
__global__ __launch_bounds__(256) void k_softmax40(float* __restrict__ dep)
{
  int i = blockIdx.x*256 + threadIdx.x;
  if (i >= 12*396) return;
  int n = i/396, p = i%396;
  float* base = dep + (size_t)n*40*396 + p;
  float mx = -1e30f;
  for (int d=0; d<40; ++d) mx = fmaxf(mx, base[(size_t)d*396]);
  float s = 0.f;
  for (int d=0; d<40; ++d){ float e = expf(base[(size_t)d*396]-mx); base[(size_t)d*396]=e; s+=e; }
  float inv = 1.f/s;
  for (int d=0; d<40; ++d) base[(size_t)d*396] *= inv;
}

// ---------- geometry ----------
__global__ __launch_bounds__(256) void k_geom(
    const float* __restrict__ rots, const float* __restrict__ trans,
    const float* __restrict__ intr, int* __restrict__ vox)
{
  int pt = blockIdx.x*256 + threadIdx.x;
  if (pt >= 190080) return;
  int b = pt/95040; int r = pt%95040;
  int n = r/15840;  int r2 = r%15840;
  int d = r2/396;   int pim = r2%396;
  int y = pim/33, x = pim%33;
  int bn = b*6+n;
  const float* R = rots + (size_t)bn*9;
  const float* T = trans + (size_t)bn*3;
  const float* K = intr + (size_t)bn*9;
  float fx=K[0], cx=K[2], fy=K[4], cy=K[5];
  float xs = (float)x * 32.96875f;
  float ys = (float)((double)y * (383.0/11.0));
  float dv = 4.0f + (float)d;
  float camx = (xs-cx)*dv/fx;
  float camy = (ys-cy)*dv/fy;
  float gx = R[0]*camx + R[1]*camy + R[2]*dv + T[0];
  float gy = R[3]*camx + R[4]*camy + R[5]*dv + T[1];
  float gz = R[6]*camx + R[7]*camy + R[8]*dv + T[2];
  int ix = (int)floorf(gx + 50.f);
  int iy = (int)floorf(gy + 50.f);
  int iz = (int)floorf((gz + 10.f)/5.f);
  bool valid = (ix>=0 && ix<100 && iy>=0 && iy<100 && iz>=0 && iz<4);
  vox[pt] = valid ? (iz*640000 + ix*100 + iy) : -1;
}

__global__ __launch_bounds__(256) void k_zero(float* __restrict__ p, int n)
{
  int i = blockIdx.x*256 + threadIdx.x;
  if (i < n) p[i] = 0.f;
}

// ---------- splat ----------
__global__ __launch_bounds__(256) void k_splat(
    const int* __restrict__ vox, const float* __restrict__ ctx,
    const float* __restrict__ dep, float* __restrict__ bev)
{
  int pt = blockIdx.x*256 + threadIdx.x;
  int c = blockIdx.y;
  if (pt >= 190080) return;
  int v = vox[pt];
  if (v < 0) return;
  int b = pt/95040; int r = pt%95040;
  int n = r/15840;  int r2 = r%15840;
  int dd = r2/396;  int pim = r2%396;
  int bn = b*6+n;
  float val = ctx[((size_t)bn*64+c)*396 + pim] * dep[((size_t)bn*40+dd)*396 + pim];
  atomicAdd(&bev[(size_t)b*2560000 + (size_t)c*10000 + v], val);
}

// ---------- BEV 3x3 conv, co-blocked: 16x16 spatial x 16 co per block ----------
// grid (49, Cout/16, 2); block 256. Thread: cq=tid&3 (4 co), pos=tid>>2:
// ly=pos>>2 (row 0..15), xq=pos&3 (x-quad). Weights pre-transposed [ci*9+tap][Cout].
__global__ __launch_bounds__(256) void k_conv3_bev2(
    const float* __restrict__ in, const float* __restrict__ Wt,
    const float* __restrict__ bns, const float* __restrict__ bnb,
    const float* __restrict__ res, float* __restrict__ out, int Cout)
{
  const int CI_CHUNK = 8;
  __shared__ __align__(16) float sw[8*144];   // [ci][tap][16co]
  __shared__ __align__(16) float st[8*324];   // [ci][18*18]
  int tid = threadIdx.x;
  int cog = blockIdx.y, b = blockIdx.z;
  int ty = (blockIdx.x/7)*16, tx = (blockIdx.x%7)*16;
  int cq = tid & 3;
  int pos = tid >> 2;
  int ly = pos >> 2;
  int x0 = (pos & 3) * 4;
  float acc[4][4];   // [x][co]
  #pragma unroll
  for (int p=0;p<4;++p)
    #pragma unroll
    for (int j=0;j<4;++j) acc[p][j]=0.f;
  const float* inb = in + (size_t)b*256*10000;
  const float* wb = Wt + cog*16;
  for (int c0=0; c0<256; c0+=CI_CHUNK){
    __syncthreads();
    for (int i=tid; i<CI_CHUNK*144; i+=256){
      int ci = i/144, r = i%144;
      sw[i] = wb[((size_t)(c0+ci)*9 + r/16)*Cout + (r%16)];
    }
    for (int i=tid; i<CI_CHUNK*324; i+=256){
      int ci = i/324, r = i%324;
      int yy = ty-1 + r/18, xx = tx-1 + r%18;
      float v = 0.f;
      if (yy>=0 && yy<100 && xx>=0 && xx<100) v = inb[(size_t)(c0+ci)*10000 + yy*100 + xx];
      st[i] = v;
    }
    __syncthreads();
    #pragma unroll 2
    for (int ci=0; ci<CI_CHUNK; ++ci){
      const float* tt = st + ci*324 + ly*18 + x0;
      const float* tw = sw + ci*144 + cq*4;
      float tv[3][6];
      #pragma unroll
      for (int r=0;r<3;++r)
        #pragma unroll
        for (int i2=0;i2<6;++i2) tv[r][i2] = tt[r*18+i2];
      #pragma unroll
      for (int r=0;r<3;++r)
        #pragma unroll
        for (int s=0;s<3;++s){
          float4 wv = *(const float4*)(tw + (r*3+s)*16);
          #pragma unroll
          for (int p=0;p<4;++p){
            float t = tv[r][p+s];
            acc[p][0] += wv.x*t; acc[p][1] += wv.y*t;
            acc[p][2] += wv.z*t; acc[p][3] += wv.w*t;
          }
        }
    }
  }
  int oy = ty + ly;
  int ox0 = tx + x0;
  if (oy < 100 && ox0 < 100){   // quad fully valid or fully invalid (both %4==0)
    #pragma unroll
    for (int j=0;j<4;++j){
      int co = cog*16 + cq*4 + j;
      float s = bns[co], bb = bnb[co];
      size_t base = ((size_t)(b*Cout+co))*10000 + (size_t)oy*100 + ox0;
      float4 v;
      v.x = fmaxf(acc[0][j]*s+bb, 0.f);
      v.y = fmaxf(acc[1][j]*s+bb, 0.f);
      v.z = fmaxf(acc[2][j]*s+bb, 0.f);
      v.w = fmaxf(acc[3][j]*s+bb, 0.f);
      if (res){
        float4 rv = *(const float4*)(res + base);
        v.x += rv.x; v.y += rv.y; v.z += rv.z; v.w += rv.w;
      }
      *(float4*)(out + base) = v;
    }
  }
}

// ---------- final 1x1 conv 128->16 ----------
__global__ __launch_bounds__(256) void k_final(
    const float* __restrict__ h, const float* __restrict__ W, const float* __restrict__ bias,
    float* __restrict__ out)
{
  int pix = blockIdx.x*256 + threadIdx.x;
  int oc = blockIdx.y, b = blockIdx.z;
  if (pix >= 10000) return;
  const float* hb = h + (size_t)b*128*10000 + pix;
  const float* w = W + (size_t)oc*128;
  float acc = bias[oc];
  for (int ci=0; ci<128; ++ci) acc += hb[(size_t)ci*10000]*w[ci];
  out[((size_t)(b*16+oc))*10000 + pix] = acc;
}

extern "C" void kernel_launch(void* const* d_in, const int* in_sizes, int n_in,
                              void* d_out, int out_size, void* d_ws, size_t ws_size,
                              hipStream_t stream)
{
  (void)in_sizes; (void)n_in; (void)out_size; (void)ws_size;
  const float* feats = (const float*)d_in[0];
  const float* rots  = (const float*)d_in[1];
  const float* trans = (const float*)d_in[2];
  const float* intr  = (const float*)d_in[3];
  const float* nw1   = (const float*)d_in[4];
  const float* bn1s  = (const float*)d_in[5];
  const float* bn1b  = (const float*)d_in[6];
  const float* se1w1 = (const float*)d_in[7];
  const float* se1b1 = (const float*)d_in[8];
  const float* se1w2 = (const float*)d_in[9];
  const float* se1b2 = (const float*)d_in[10];
  const float* nw2   = (const float*)d_in[11];
  const float* bn2s  = (const float*)d_in[12];
  const float* bn2b  = (const float*)d_in[13];
  const float* dhw   = (const float*)d_in[14];
  const float* dhb   = (const float*)d_in[15];
  const float* chw   = (const float*)d_in[16];
  const float* chb   = (const float*)d_in[17];
  const float* bcw1  = (const float*)d_in[18];
  const float* bcs1  = (const float*)d_in[19];
  const float* bcb1  = (const float*)d_in[20];
  const float* bcsw1 = (const float*)d_in[21];
  const float* bcsb1 = (const float*)d_in[22];
  const float* bcsw2 = (const float*)d_in[23];
  const float* bcsb2 = (const float*)d_in[24];
  const float* bcw2  = (const float*)d_in[25];
  const float* bcs2  = (const float*)d_in[26];
  const float* bcb2  = (const float*)d_in[27];
  const float* dw1   = (const float*)d_in[28];
  const float* ds1   = (const float*)d_in[29];
  const float* db1   = (const float*)d_in[30];
  const float* dw2   = (const float*)d_in[31];
  const float* db2   = (const float*)d_in[32];
  float* out = (float*)d_out;

  // workspace layout (floats)
  float* ws    = (float*)d_ws;
  float* x1    = ws;                    // 1216512
  float* x2    = x1 + 1216512;          // 1216512
  float* dep   = x2 + 1216512;          // 190080
  float* ctx   = dep + 190080;          // 304128
  float* mean1 = ctx + 304128;          // 3072
  float* g1    = mean1 + 3072;          // 3072
  int*   vox   = (int*)(g1 + 3072);     // 190080 ints
  float* bev   = (float*)(vox + 190080);// 5120000
  float* h1    = bev + 5120000;         // 5120000
  float* mean2 = h1 + 5120000;          // 512
  float* g2    = mean2 + 512;           // 512
  float* h3    = g2 + 512;              // 2560000
  // aliased transposed weights (placed in dead regions):
  float* WtA = bev;            // nw2^T (589824)    — dead once conv3_small2 done (before k_zero)
  float* Wt1 = x1;             // bcw1^T (589824)   — x1 dead after conv3_small2
  float* Wt3 = x1 + 589824;    // dw1^T  (294912)
  float* Wt2 = x2;             // bcw2^T (589824)   — x2 dead after k_heads

  // image branch
  k_conv1<<<dim3(2,32,12),256,0,stream>>>(feats,nw1,bn1s,bn1b,x1);
  k_rowmean<<<3072,256,0,stream>>>(x1,mean1,396,1.f/396.f);
  k_se_fc<<<12,256,0,stream>>>(mean1,se1w1,se1b1,se1w2,se1b2,g1,32);
  k_scale<<<(1216512+255)/256,256,0,stream>>>(x1,g1,396,1216512);
  k_wtrans<<<(589824+255)/256,256,0,stream>>>(nw2,WtA,256);
  k_conv3_small2<<<dim3(32,12),256,0,stream>>>(x1,WtA,bn2s,bn2b,x2);
  k_heads<<<dim3(2,104,12),256,0,stream>>>(x2,dhw,dhb,chw,chb,dep,ctx);
  k_softmax40<<<(4752+255)/256,256,0,stream>>>(dep);

  // transposes for BEV convs (x1, x2 now dead)
  k_wtrans<<<(589824+255)/256,256,0,stream>>>(bcw1,Wt1,256);
  k_wtrans<<<(589824+255)/256,256,0,stream>>>(bcw2,Wt2,256);
  k_wtrans<<<(294912+255)/256,256,0,stream>>>(dw1,Wt3,128);

  // lift-splat
  k_geom<<<(190080+255)/256,256,0,stream>>>(rots,trans,intr,vox);
  k_zero<<<(5120000+255)/256,256,0,stream>>>(bev,5120000);
  k_splat<<<dim3(743,64),256,0,stream>>>(vox,ctx,dep,bev);

  // BEV encoder
  k_conv3_bev2<<<dim3(49,16,2),256,0,stream>>>(bev,Wt1,bcs1,bcb1,nullptr,h1,256);
  k_rowmean<<<512,256,0,stream>>>(h1,mean2,10000,1e-4f);
  k_se_fc<<<2,256,0,stream>>>(mean2,bcsw1,bcsb1,bcsw2,bcsb2,g2,16);
  k_scale<<<(5120000+255)/256,256,0,stream>>>(h1,g2,10000,5120000);
  k_conv3_bev2<<<dim3(49,16,2),256,0,stream>>>(h1,Wt2,bcs2,bcb2,bev,bev,256);
  k_conv3_bev2<<<dim3(49,8,2),256,0,stream>>>(bev,Wt3,ds1,db1,nullptr,h3,128);
  k_final<<<dim3(40,16,2),256,0,stream>>>(h3,dw2,db2,out);
}

// Round 3
// 1220.050 us; speedup vs baseline: 7.6830x; 1.9829x over previous
//
#include <hip/hip_runtime.h>
#include <hip/hip_bf16.h>
#include <cmath>

// LSS pipeline R3: MFMA bf16-split BEV convs + gather-based splat (no value atomics).

typedef __attribute__((ext_vector_type(8))) short short8;
typedef __attribute__((ext_vector_type(4))) float floatx4;
typedef __hip_bfloat16 hb;

__device__ __forceinline__ float sigf(float x){ return 1.0f/(1.0f+expf(-x)); }
__device__ __forceinline__ float siluf(float x){ return x*sigf(x); }

// ---------- K1: 1x1 conv 1280->256 + BN + SiLU ----------
__global__ __launch_bounds__(256) void k_conv1(
    const float* __restrict__ feats, const float* __restrict__ W,
    const float* __restrict__ bns, const float* __restrict__ bnb,
    float* __restrict__ out)
{
  int p = blockIdx.x*256 + threadIdx.x;
  int cog = blockIdx.y; int n = blockIdx.z;
  if (p >= 396) return;
  float acc[8];
  #pragma unroll
  for (int j=0;j<8;++j) acc[j]=0.f;
  const float* f = feats + (size_t)n*1280*396 + p;
  const float* w = W + (size_t)cog*8*1280;
  for (int ci=0; ci<1280; ++ci){
    float fv = f[(size_t)ci*396];
    #pragma unroll
    for (int j=0;j<8;++j) acc[j] += fv * w[j*1280+ci];
  }
  #pragma unroll
  for (int j=0;j<8;++j){
    int co = cog*8+j;
    float v = acc[j]*bns[co]+bnb[co];
    out[((size_t)n*256+co)*396 + p] = siluf(v);
  }
}

// ---------- row mean ----------
__global__ __launch_bounds__(256) void k_rowmean(
    const float* __restrict__ in, float* __restrict__ out, int rowlen, float inv)
{
  __shared__ float ws[4];
  int row = blockIdx.x; int t = threadIdx.x;
  const float* p = in + (size_t)row*rowlen;
  float s = 0.f;
  for (int i=t; i<rowlen; i+=256) s += p[i];
  #pragma unroll
  for (int off=32; off; off>>=1) s += __shfl_down(s, off);
  if ((t&63)==0) ws[t>>6] = s;
  __syncthreads();
  if (t==0) out[row] = (ws[0]+ws[1]+ws[2]+ws[3]) * inv;
}

// ---------- SE FC ----------
__global__ __launch_bounds__(256) void k_se_fc(
    const float* __restrict__ mean, const float* __restrict__ w1, const float* __restrict__ b1,
    const float* __restrict__ w2, const float* __restrict__ b2, float* __restrict__ g, int H)
{
  __shared__ float m[256];
  __shared__ float h[32];
  int n = blockIdx.x; int t = threadIdx.x;
  m[t] = mean[n*256 + t];
  __syncthreads();
  if (t < H){
    float s = b1[t];
    for (int c=0; c<256; ++c) s += m[c]*w1[t*256+c];
    h[t] = siluf(s);
  }
  __syncthreads();
  float s = b2[t];
  for (int j=0; j<H; ++j) s += h[j]*w2[t*H+j];
  g[n*256+t] = sigf(s);
}

// ---------- scale rows by g ----------
__global__ __launch_bounds__(256) void k_scale(
    float* __restrict__ x, const float* __restrict__ g, int rowlen, int total)
{
  int i = blockIdx.x*256 + threadIdx.x;
  if (i < total){ int row = i / rowlen; x[i] *= g[row]; }
}

// ---------- weight transpose (image 3x3 conv): W[co][ci][tap] -> Wt[ci*9+tap][co] ----------
__global__ __launch_bounds__(256) void k_wtrans(
    const float* __restrict__ W, float* __restrict__ Wt, int Cout)
{
  int i = blockIdx.x*256 + threadIdx.x;
  int total = Cout*2304;
  if (i >= total) return;
  int co = i / 2304;
  int r  = i % 2304;
  Wt[(size_t)r*Cout + co] = W[i];
}

// ---------- 3x3 conv on 12x33 (image branch), co-blocked, BN+SiLU ----------
__global__ __launch_bounds__(256) void k_conv3_small2(
    const float* __restrict__ in, const float* __restrict__ Wt,
    const float* __restrict__ bns, const float* __restrict__ bnb,
    float* __restrict__ out)
{
  const int CI_CHUNK = 8;
  __shared__ __align__(16) float sw[8*72];
  __shared__ __align__(16) float st[8*532];
  int tid = threadIdx.x;
  int cog = blockIdx.x, n = blockIdx.y;
  int cq = tid >> 7;
  int pos = tid & 127;
  int y = pos / 9, xq = pos % 9;
  int x0 = xq * 4;
  bool active = pos < 108;
  float acc[4][4];
  #pragma unroll
  for (int p=0;p<4;++p)
    #pragma unroll
    for (int j=0;j<4;++j) acc[p][j]=0.f;
  const float* inb = in + (size_t)n*256*396;
  for (int c0=0; c0<256; c0+=CI_CHUNK){
    __syncthreads();
    for (int i=tid; i<CI_CHUNK*72; i+=256){
      int ci = i/72, r = i%72;
      int tap = r/8, j = r%8;
      sw[i] = Wt[((size_t)(c0+ci)*9 + tap)*256 + cog*8 + j];
    }
    for (int i=tid; i<CI_CHUNK*532; i+=256){
      int ci = i/532, r = i%532;
      int yy = r/38 - 1, xx = r%38 - 1;
      float v = 0.f;
      if (yy>=0 && yy<12 && xx>=0 && xx<33) v = inb[(size_t)(c0+ci)*396 + yy*33 + xx];
      st[i] = v;
    }
    __syncthreads();
    if (active){
      #pragma unroll 2
      for (int ci=0; ci<CI_CHUNK; ++ci){
        const float* tt = st + ci*532 + y*38 + x0;
        const float* tw = sw + ci*72 + cq*4;
        float tv[3][6];
        #pragma unroll
        for (int r=0;r<3;++r)
          #pragma unroll
          for (int i2=0;i2<6;++i2) tv[r][i2] = tt[r*38+i2];
        #pragma unroll
        for (int r=0;r<3;++r)
          #pragma unroll
          for (int s=0;s<3;++s){
            float4 wv = *(const float4*)(tw + (r*3+s)*8);
            #pragma unroll
            for (int p=0;p<4;++p){
              float t = tv[r][p+s];
              acc[p][0] += wv.x*t; acc[p][1] += wv.y*t;
              acc[p][2] += wv.z*t; acc[p][3] += wv.w*t;
            }
          }
      }
    }
  }
  if (active){
    #pragma unroll
    for (int j=0;j<4;++j){
      int co = cog*8 + cq*4 + j;
      float s = bns[co], bb = bnb[co];
      size_t base = ((size_t)n*256+co)*396 + y*33;
      #pragma unroll
      for (int p=0;p<4;++p){
        int ox = x0+p;
        if (ox < 33) out[base+ox] = siluf(acc[p][j]*s+bb);
      }
    }
  }
}

// ---------- heads: depth (40, NCHW) and ctx (64, NHWC!) ----------
__global__ __launch_bounds__(256) void k_heads(
    const float* __restrict__ x, const float* __restrict__ dhw, const float* __restrict__ dhb,
    const float* __restrict__ chw, const float* __restrict__ chb,
    float* __restrict__ dep, float* __restrict__ ctx2)
{
  int p = blockIdx.x*256 + threadIdx.x;
  int co = blockIdx.y; int n = blockIdx.z;
  if (p >= 396) return;
  const float* xb = x + (size_t)n*256*396 + p;
  const float* w = (co < 40) ? (dhw + (size_t)co*256) : (chw + (size_t)(co-40)*256);
  float acc = 0.f;
  for (int ci=0; ci<256; ++ci) acc += xb[(size_t)ci*396] * w[ci];
  if (co < 40) dep[((size_t)n*40+co)*396 + p] = acc + dhb[co];
  else { int c = co-40; ctx2[((size_t)n*396+p)*64 + c] = acc + chb[c]; }
}

// ---------- softmax over 40 depth channels ----------
__global__ __launch_bounds__(256) void k_softmax40(float* __restrict__ dep)
{
  int i = blockIdx.x*256 + threadIdx.x;
  if (i >= 12*396) return;
  int n = i/396, p = i%396;
  float* base = dep + (size_t)n*40*396 + p;
  float mx = -1e30f;
  for (int d=0; d<40; ++d) mx = fmaxf(mx, base[(size_t)d*396]);
  float s = 0.f;
  for (int d=0; d<40; ++d){ float e = expf(base[(size_t)d*396]-mx); base[(size_t)d*396]=e; s+=e; }
  float inv = 1.f/s;
  for (int d=0; d<40; ++d) base[(size_t)d*396] *= inv;
}

// ---------- geometry: per frustum point -> sid in [0,40000) or -1 ----------
__global__ __launch_bounds__(256) void k_geom(
    const float* __restrict__ rots, const float* __restrict__ trans,
    const float* __restrict__ intr, int* __restrict__ vox)
{
  int pt = blockIdx.x*256 + threadIdx.x;
  if (pt >= 190080) return;
  int b = pt/95040; int r = pt%95040;
  int n = r/15840;  int r2 = r%15840;
  int d = r2/396;   int pim = r2%396;
  int y = pim/33, x = pim%33;
  int bn = b*6+n;
  const float* R = rots + (size_t)bn*9;
  const float* T = trans + (size_t)bn*3;
  const float* K = intr + (size_t)bn*9;
  float fx=K[0], cx=K[2], fy=K[4], cy=K[5];
  float xs = (float)x * 32.96875f;
  float ys = (float)((double)y * (383.0/11.0));
  float dv = 4.0f + (float)d;
  float camx = (xs-cx)*dv/fx;
  float camy = (ys-cy)*dv/fy;
  float gx = R[0]*camx + R[1]*camy + R[2]*dv + T[0];
  float gy = R[3]*camx + R[4]*camy + R[5]*dv + T[1];
  float gz = R[6]*camx + R[7]*camy + R[8]*dv + T[2];
  int ix = (int)floorf(gx + 50.f);
  int iy = (int)floorf(gy + 50.f);
  int iz = (int)floorf((gz + 10.f)/5.f);
  bool valid = (ix>=0 && ix<100 && iy>=0 && iy<100 && iz>=0 && iz<4);
  vox[pt] = valid ? (iz*10000 + ix*100 + iy) : -1;
}

// ---------- splat as gather: count -> scan -> fill -> gather ----------
__global__ __launch_bounds__(256) void k_count(
    const int* __restrict__ vox, int* __restrict__ cnt)
{
  int pt = blockIdx.x*256 + threadIdx.x;
  if (pt >= 190080) return;
  int s = vox[pt];
  if (s < 0) return;
  int b = pt/95040;
  atomicAdd(&cnt[b*40000 + s], 1);
}

__global__ __launch_bounds__(256) void k_scan1(
    const int* __restrict__ cnt, int* __restrict__ off, int* __restrict__ bsum)
{
  __shared__ int s[256];
  int t = threadIdx.x;
  int i = blockIdx.x*256 + t;
  int v = (i < 80000) ? cnt[i] : 0;
  s[t] = v; __syncthreads();
  for (int o=1;o<256;o<<=1){
    int x = (t>=o) ? s[t-o] : 0;
    __syncthreads();
    s[t] += x;
    __syncthreads();
  }
  if (i < 80000) off[i] = s[t] - v;
  if (t == 255) bsum[blockIdx.x] = s[255];
}

__global__ void k_scan2(int* __restrict__ bsum, int nblk)
{
  if (threadIdx.x==0 && blockIdx.x==0){
    int run = 0;
    for (int j=0;j<nblk;++j){ int t = bsum[j]; bsum[j] = run; run += t; }
  }
}

__global__ __launch_bounds__(256) void k_scan3(
    int* __restrict__ off, const int* __restrict__ bsum, int* __restrict__ cur)
{
  int i = blockIdx.x*256 + threadIdx.x;
  if (i >= 80000) return;
  int o = off[i] + bsum[i>>8];
  off[i] = o;
  cur[i] = o;
}

__global__ __launch_bounds__(256) void k_fill(
    const int* __restrict__ vox, int* __restrict__ cur, int* __restrict__ list)
{
  int pt = blockIdx.x*256 + threadIdx.x;
  if (pt >= 190080) return;
  int s = vox[pt];
  if (s < 0) return;
  int b = pt/95040;
  int slot = atomicAdd(&cur[b*40000 + s], 1);
  list[slot] = pt;
}

// one wave per (b,sid); lane = channel. Writes every bev element (no zeroing needed).
__global__ __launch_bounds__(256) void k_gather(
    const int* __restrict__ off, const int* __restrict__ cnt, const int* __restrict__ list,
    const float* __restrict__ ctx2, const float* __restrict__ dep, float* __restrict__ bev)
{
  int tid = threadIdx.x;
  int bv = blockIdx.x*4 + (tid>>6);
  int c = tid & 63;
  int b = bv/40000, sid = bv%40000;
  int st = off[bv], nn = cnt[bv];
  float s = 0.f;
  for (int k=0;k<nn;++k){
    int pt = list[st+k];
    int r = pt%95040;
    int bn = b*6 + r/15840;
    int r2 = r%15840;
    int dd = r2/396, pim = r2%396;
    s += ctx2[((size_t)bn*396+pim)*64 + c] * dep[((size_t)bn*40+dd)*396 + pim];
  }
  int iz = sid/10000, rem = sid%10000;
  bev[(size_t)b*2560000 + (size_t)iz*640000 + (size_t)c*10000 + rem] = s;
}

// ---------- NCHW fp32 -> padded NHWC bf16 hi/lo [b][102][102][256] ----------
__global__ __launch_bounds__(256) void k_tohwc(
    const float* __restrict__ in, hb* __restrict__ Ah, hb* __restrict__ Al)
{
  int y = blockIdx.x;      // 0..101
  int b = blockIdx.y;
  int ci = threadIdx.x;
  for (int x=0; x<102; ++x){
    float v = 0.f;
    if (y>=1 && y<=100 && x>=1 && x<=100)
      v = in[(((size_t)b*256 + ci)*100 + (y-1))*100 + (x-1)];
    hb hv = __float2bfloat16(v);
    hb lv = __float2bfloat16(v - __bfloat162float(hv));
    size_t o = (((size_t)b*102 + y)*102 + x)*256 + ci;
    Ah[o] = hv; Al[o] = lv;
  }
}

// ---------- weight pack into MFMA B-frag order, hi/lo split ----------
// Wp[(((tap*8+kb)*NB + nb)*64 + lane)*8 + j] = W[co=nb*16+(lane&15)][ci=kb*32+(lane>>4)*8+j][tap]
__global__ __launch_bounds__(256) void k_wpack(
    const float* __restrict__ W, hb* __restrict__ Wph, hb* __restrict__ Wpl, int NB)
{
  int i = blockIdx.x*256 + threadIdx.x;
  int total = 9*8*NB*512;
  if (i >= total) return;
  int j = i & 7;
  int t1 = i >> 3;
  int lane = t1 & 63;
  int t2 = t1 >> 6;
  int nb = t2 % NB;
  int t3 = t2 / NB;
  int kb = t3 & 7;
  int tap = t3 >> 3;
  int ci = kb*32 + (lane>>4)*8 + j;
  int co = nb*16 + (lane&15);
  float w = W[(size_t)co*2304 + ci*9 + tap];
  hb hv = __float2bfloat16(w);
  hb lv = __float2bfloat16(w - __bfloat162float(hv));
  Wph[i] = hv; Wpl[i] = lv;
}

// ---------- MFMA 3x3 conv: block = 16x x 8y x 64co, 4 waves (wave = rows y0,y0+4) ----------
__device__ __forceinline__ void a_addrs(int idx, int bb, int x0, int y0, int m, int q,
                                        size_t* o0, size_t* o1)
{
  int tap = idx >> 3, kb = idx & 7;
  int dy = (tap*11) >> 5;       // tap/3 for tap<9
  int dx = tap - dy*3;
  int xA = x0 + dx + m; xA = xA > 101 ? 101 : xA;
  int yA0 = y0 + dy;     yA0 = yA0 > 101 ? 101 : yA0;
  int yA1 = y0 + 4 + dy; yA1 = yA1 > 101 ? 101 : yA1;
  // offsets in short8 units: element_off/8 = ((bb*102+y)*102+x)*32 + kb*4 + q
  *o0 = (size_t)((bb*102 + yA0)*102 + xA)*32 + kb*4 + q;
  *o1 = (size_t)((bb*102 + yA1)*102 + xA)*32 + kb*4 + q;
}

__global__ __launch_bounds__(256) void k_conv3_mfma(
    const hb* __restrict__ Ah, const hb* __restrict__ Al,
    const hb* __restrict__ Wph, const hb* __restrict__ Wpl,
    const float* __restrict__ bns, const float* __restrict__ bnb,
    const float* __restrict__ res, float* __restrict__ out, int Cout)
{
  __shared__ short8 lbh[256], lbl[256];
  const int NB = Cout >> 4;
  int tid = threadIdx.x;
  int wv = tid >> 6, lane = tid & 63;
  int xg = blockIdx.x % 7, yg = blockIdx.x / 7;
  int cog = blockIdx.y, bb = blockIdx.z;
  int x0 = xg*16;
  int y0 = yg*8 + wv;
  int m = lane & 15, q = lane >> 4;
  int nb0 = cog*4;
  floatx4 acc[2][4];
  #pragma unroll
  for (int i=0;i<2;++i)
    #pragma unroll
    for (int j=0;j<4;++j) acc[i][j] = (floatx4)(0.f);

  const short8* gAh = (const short8*)(const void*)Ah;
  const short8* gAl = (const short8*)(const void*)Al;
  const short8* gWh = (const short8*)(const void*)Wph;
  const short8* gWl = (const short8*)(const void*)Wpl;
  const size_t nbstride = (size_t)NB*64;
  const size_t sb = (size_t)(nb0 + wv)*64 + lane;   // this thread's stage slot

  size_t o0,o1;
  a_addrs(0, bb, x0, y0, m, q, &o0, &o1);
  short8 cah0 = gAh[o0], cal0 = gAl[o0], cah1 = gAh[o1], cal1 = gAl[o1];
  short8 ph = gWh[sb], pl = gWl[sb];

  for (int idx=0; idx<72; ++idx){
    __syncthreads();                 // previous iteration's LDS reads done
    lbh[tid] = ph;
    lbl[tid] = pl;
    int nx = (idx+1 < 72) ? idx+1 : 71;
    ph = gWh[(size_t)nx*nbstride + sb];
    pl = gWl[(size_t)nx*nbstride + sb];
    __syncthreads();                 // staged B visible
    size_t n0,n1;
    a_addrs(nx, bb, x0, y0, m, q, &n0, &n1);
    short8 nah0 = gAh[n0], nal0 = gAl[n0], nah1 = gAh[n1], nal1 = gAl[n1];
    #pragma unroll
    for (int nb=0; nb<4; ++nb){
      short8 bh = lbh[nb*64 + lane];
      short8 bl = lbl[nb*64 + lane];
      acc[0][nb] = __builtin_amdgcn_mfma_f32_16x16x32_bf16(cah0, bh, acc[0][nb], 0,0,0);
      acc[0][nb] = __builtin_amdgcn_mfma_f32_16x16x32_bf16(cah0, bl, acc[0][nb], 0,0,0);
      acc[0][nb] = __builtin_amdgcn_mfma_f32_16x16x32_bf16(cal0, bh, acc[0][nb], 0,0,0);
      acc[1][nb] = __builtin_amdgcn_mfma_f32_16x16x32_bf16(cah1, bh, acc[1][nb], 0,0,0);
      acc[1][nb] = __builtin_amdgcn_mfma_f32_16x16x32_bf16(cah1, bl, acc[1][nb], 0,0,0);
      acc[1][nb] = __builtin_amdgcn_mfma_f32_16x16x32_bf16(cal1, bh, acc[1][nb], 0,0,0);
    }
    cah0 = nah0; cal0 = nal0; cah1 = nah1; cal1 = nal1;
  }

  // epilogue: D row = q*4+reg -> x, D col = lane&15 -> co
  int n = lane & 15;
  int xq = x0 + q*4;
  #pragma unroll
  for (int mg=0; mg<2; ++mg){
    int yo = y0 + mg*4;
    if (yo < 100 && xq < 100){
      #pragma unroll
      for (int nb=0; nb<4; ++nb){
        int co = cog*64 + nb*16 + n;
        float s = bns[co], bv = bnb[co];
        floatx4 a = acc[mg][nb];
        float4 v;
        v.x = fmaxf(a[0]*s+bv, 0.f);
        v.y = fmaxf(a[1]*s+bv, 0.f);
        v.z = fmaxf(a[2]*s+bv, 0.f);
        v.w = fmaxf(a[3]*s+bv, 0.f);
        size_t o = ((size_t)(bb*Cout+co)*100 + yo)*100 + xq;
        if (res){
          float4 rv = *(const float4*)(res + o);
          v.x += rv.x; v.y += rv.y; v.z += rv.z; v.w += rv.w;
        }
        *(float4*)(out + o) = v;
      }
    }
  }
}

// ---------- final 1x1 conv 128->16 ----------
__global__ __launch_bounds__(256) void k_final(
    const float* __restrict__ h, const float* __restrict__ W, const float* __restrict__ bias,
    float* __restrict__ out)
{
  int pix = blockIdx.x*256 + threadIdx.x;
  int oc = blockIdx.y, b = blockIdx.z;
  if (pix >= 10000) return;
  const float* hb_ = h + (size_t)b*128*10000 + pix;
  const float* w = W + (size_t)oc*128;
  float acc = bias[oc];
  for (int ci=0; ci<128; ++ci) acc += hb_[(size_t)ci*10000]*w[ci];
  out[((size_t)(b*16+oc))*10000 + pix] = acc;
}

extern "C" void kernel_launch(void* const* d_in, const int* in_sizes, int n_in,
                              void* d_out, int out_size, void* d_ws, size_t ws_size,
                              hipStream_t stream)
{
  (void)in_sizes; (void)n_in; (void)out_size; (void)ws_size;
  const float* feats = (const float*)d_in[0];
  const float* rots  = (const float*)d_in[1];
  const float* trans = (const float*)d_in[2];
  const float* intr  = (const float*)d_in[3];
  const float* nw1   = (const float*)d_in[4];
  const float* bn1s  = (const float*)d_in[5];
  const float* bn1b  = (const float*)d_in[6];
  const float* se1w1 = (const float*)d_in[7];
  const float* se1b1 = (const float*)d_in[8];
  const float* se1w2 = (const float*)d_in[9];
  const float* se1b2 = (const float*)d_in[10];
  const float* nw2   = (const float*)d_in[11];
  const float* bn2s  = (const float*)d_in[12];
  const float* bn2b  = (const float*)d_in[13];
  const float* dhw   = (const float*)d_in[14];
  const float* dhb   = (const float*)d_in[15];
  const float* chw   = (const float*)d_in[16];
  const float* chb   = (const float*)d_in[17];
  const float* bcw1  = (const float*)d_in[18];
  const float* bcs1  = (const float*)d_in[19];
  const float* bcb1  = (const float*)d_in[20];
  const float* bcsw1 = (const float*)d_in[21];
  const float* bcsb1 = (const float*)d_in[22];
  const float* bcsw2 = (const float*)d_in[23];
  const float* bcsb2 = (const float*)d_in[24];
  const float* bcw2  = (const float*)d_in[25];
  const float* bcs2  = (const float*)d_in[26];
  const float* bcb2  = (const float*)d_in[27];
  const float* dw1   = (const float*)d_in[28];
  const float* ds1   = (const float*)d_in[29];
  const float* db1   = (const float*)d_in[30];
  const float* dw2   = (const float*)d_in[31];
  const float* db2   = (const float*)d_in[32];
  float* out = (float*)d_out;

  // ---- workspace layout (float units) ----
  float* ws = (float*)d_ws;
  float* bev   = ws;                       // S0: 5,120,000
  float* h1    = ws + 5120000;             // S1: 5,120,000 (aliases: x1, splat arrays, h3)
  hb*    Ah    = (hb*)(ws + 10240000);     // S2: 2,663,424 fu (5,326,848 bf16)
  hb*    Al    = (hb*)(ws + 12903424);     // S3: 2,663,424 fu
  float* x2    = ws + 15566848;            // S4: 1,216,512 (later Wp1h/l, Wp3h/l)
  float* S5    = ws + 16783360;            // 589,824 (Wp2h/l)
  float* dep   = ws + 17373184;            // 190,080
  float* ctx2  = ws + 17563264;            // 304,128 (NHWC)
  float* mean1 = ws + 17867392;            // 3072
  float* g1    = mean1 + 3072;             // 3072
  float* mean2 = g1 + 3072;                // 512
  float* g2    = mean2 + 512;              // 512
  int*   vox   = (int*)(ws + 17875584);    // 190,080 ints
  // aliases
  float* x1    = h1;                       // image feature (dead before gather phase)
  int*   cnt   = (int*)(h1 + 1300000);     // 80,000
  int*   off   = cnt + 80000;              // 80,000
  int*   cur   = off + 80000;              // 80,000
  int*   bsum  = cur + 80000;              // 1,024
  int*   list  = bsum + 1024;              // 190,080
  float* h3    = h1;                       // conv3 out (h1 dead by then)
  float* WtA   = bev;                      // image conv weights (dead before gather)
  hb* Wp1h = (hb*)x2;                      // 589,824 bf16
  hb* Wp1l = (hb*)(x2 + 294912);
  hb* Wp3h = (hb*)(x2 + 589824);           // 294,912 bf16
  hb* Wp3l = (hb*)(x2 + 589824 + 147456);
  hb* Wp2h = (hb*)S5;
  hb* Wp2l = (hb*)(S5 + 294912);

  // ---- image branch ----
  k_conv1<<<dim3(2,32,12),256,0,stream>>>(feats,nw1,bn1s,bn1b,x1);
  k_rowmean<<<3072,256,0,stream>>>(x1,mean1,396,1.f/396.f);
  k_se_fc<<<12,256,0,stream>>>(mean1,se1w1,se1b1,se1w2,se1b2,g1,32);
  k_scale<<<(1216512+255)/256,256,0,stream>>>(x1,g1,396,1216512);
  k_wtrans<<<(589824+255)/256,256,0,stream>>>(nw2,WtA,256);
  k_conv3_small2<<<dim3(32,12),256,0,stream>>>(x1,WtA,bn2s,bn2b,x2);
  k_heads<<<dim3(2,104,12),256,0,stream>>>(x2,dhw,dhb,chw,chb,dep,ctx2);
  k_softmax40<<<(4752+255)/256,256,0,stream>>>(dep);

  // ---- pack BEV conv weights (x2 dead after k_heads) ----
  k_wpack<<<(589824+255)/256,256,0,stream>>>(bcw1,Wp1h,Wp1l,16);
  k_wpack<<<(589824+255)/256,256,0,stream>>>(bcw2,Wp2h,Wp2l,16);
  k_wpack<<<(294912+255)/256,256,0,stream>>>(dw1,Wp3h,Wp3l,8);

  // ---- lift-splat (gather form) ----
  k_geom<<<(190080+255)/256,256,0,stream>>>(rots,trans,intr,vox);
  hipMemsetAsync(cnt, 0, 80000*sizeof(int), stream);
  k_count<<<(190080+255)/256,256,0,stream>>>(vox,cnt);
  k_scan1<<<313,256,0,stream>>>(cnt,off,bsum);
  k_scan2<<<1,64,0,stream>>>(bsum,313);
  k_scan3<<<(80000+255)/256,256,0,stream>>>(off,bsum,cur);
  k_fill<<<(190080+255)/256,256,0,stream>>>(vox,cur,list);
  k_gather<<<20000,256,0,stream>>>(off,cnt,list,ctx2,dep,bev);

  // ---- BEV encoder (MFMA convs) ----
  k_tohwc<<<dim3(102,2),256,0,stream>>>(bev,Ah,Al);
  k_conv3_mfma<<<dim3(91,4,2),256,0,stream>>>(Ah,Al,Wp1h,Wp1l,bcs1,bcb1,nullptr,h1,256);
  k_rowmean<<<512,256,0,stream>>>(h1,mean2,10000,1e-4f);
  k_se_fc<<<2,256,0,stream>>>(mean2,bcsw1,bcsb1,bcsw2,bcsb2,g2,16);
  k_scale<<<(5120000+255)/256,256,0,stream>>>(h1,g2,10000,5120000);
  k_tohwc<<<dim3(102,2),256,0,stream>>>(h1,Ah,Al);
  k_conv3_mfma<<<dim3(91,4,2),256,0,stream>>>(Ah,Al,Wp2h,Wp2l,bcs2,bcb2,bev,bev,256);
  k_tohwc<<<dim3(102,2),256,0,stream>>>(bev,Ah,Al);
  k_conv3_mfma<<<dim3(91,2,2),256,0,stream>>>(Ah,Al,Wp3h,Wp3l,ds1,db1,nullptr,h3,128);
  k_final<<<dim3(40,16,2),256,0,stream>>>(h3,dw2,db2,out);
}

// Round 6
// 986.120 us; speedup vs baseline: 9.5056x; 1.2372x over previous
//
#include <hip/hip_runtime.h>
#include <hip/hip_bf16.h>
#include <cmath>

// LSS pipeline R6: R5 + fix second packed-weight overlap (Wc1l was at
// Wc1h+81920 fu but Wc1h is 163840 fu; now at bev+3205120).

typedef __attribute__((ext_vector_type(8))) short short8;
typedef __attribute__((ext_vector_type(4))) float floatx4;
typedef __hip_bfloat16 hb;

__device__ __forceinline__ float sigf(float x){ return 1.0f/(1.0f+expf(-x)); }
__device__ __forceinline__ float siluf(float x){ return x*sigf(x); }
__device__ __forceinline__ void split2(float v, hb* h, hb* l){
  hb hv = __float2bfloat16(v);
  *h = hv; *l = __float2bfloat16(v - __bfloat162float(hv));
}

// ---------- feats NCHW -> NHWC bf16 hi/lo [n][396][1280] ----------
__global__ __launch_bounds__(256) void k_trans_feats(
    const float* __restrict__ feats, hb* __restrict__ Fh, hb* __restrict__ Fl)
{
  __shared__ float tile[64][65];
  int n = blockIdx.y;
  int p0 = blockIdx.x*64;
  int tid = threadIdx.x;
  int tr = tid >> 6;      // 0..3
  int tc = tid & 63;
  for (int c0=0; c0<1280; c0+=64){
    __syncthreads();
    #pragma unroll
    for (int it=0; it<16; ++it){
      int ci = c0 + it*4 + tr;
      int p = p0 + tc;
      float v = 0.f;
      if (p < 396) v = feats[((size_t)n*1280 + ci)*396 + p];
      tile[it*4+tr][tc] = v;
    }
    __syncthreads();
    #pragma unroll
    for (int it=0; it<16; ++it){
      int pl = it*4 + tr;
      int p = p0 + pl;
      if (p < 396){
        hb hv, lv; split2(tile[tc][pl], &hv, &lv);
        size_t o = ((size_t)n*396 + p)*1280 + c0 + tc;
        Fh[o] = hv; Fl[o] = lv;
      }
    }
  }
}

// ---------- pack 1x1 weights [256][1280] -> [(kb*16+nb)*64+lane][8] ----------
__global__ __launch_bounds__(256) void k_wpack1(
    const float* __restrict__ W, hb* __restrict__ Wph, hb* __restrict__ Wpl)
{
  int i = blockIdx.x*256 + threadIdx.x;
  if (i >= 40*16*512) return;
  int j = i & 7;
  int lane = (i>>3) & 63;
  int t2 = i >> 9;
  int nb = t2 & 15;
  int kb = t2 >> 4;
  int ci = kb*32 + (lane>>4)*8 + j;
  int co = nb*16 + (lane&15);
  hb hv, lv; split2(W[(size_t)co*1280 + ci], &hv, &lv);
  Wph[i] = hv; Wpl[i] = lv;
}

// ---------- pack 3x3 weights [co][ci][9] -> [((tap*8+kb)*NB+nb)*64+lane][8] ----------
__global__ __launch_bounds__(256) void k_wpack(
    const float* __restrict__ W, hb* __restrict__ Wph, hb* __restrict__ Wpl, int NB)
{
  int i = blockIdx.x*256 + threadIdx.x;
  int total = 9*8*NB*512;
  if (i >= total) return;
  int j = i & 7;
  int t1 = i >> 3;
  int lane = t1 & 63;
  int t2 = t1 >> 6;
  int nb = t2 % NB;
  int t3 = t2 / NB;
  int kb = t3 & 7;
  int tap = t3 >> 3;
  int ci = kb*32 + (lane>>4)*8 + j;
  int co = nb*16 + (lane&15);
  hb hv, lv; split2(W[(size_t)co*2304 + ci*9 + tap], &hv, &lv);
  Wph[i] = hv; Wpl[i] = lv;
}

// ---------- conv1 as MFMA GEMM: M=4752 (pix), N=256, K=1280; BN+SiLU; out NHWC ----------
__global__ __launch_bounds__(256) void k_mfma_gemm1(
    const hb* __restrict__ Fh, const hb* __restrict__ Fl,
    const hb* __restrict__ Wph, const hb* __restrict__ Wpl,
    const float* __restrict__ bns, const float* __restrict__ bnb,
    float* __restrict__ out)
{
  __shared__ short8 lbh[256], lbl[256];
  int tid = threadIdx.x;
  int wv = tid >> 6, lane = tid & 63;
  int cog = blockIdx.y;
  int Pbase = blockIdx.x*128 + wv*32;
  int m = lane & 15, q = lane >> 4;
  int P0 = Pbase + m;      if (P0 > 4751) P0 = 4751;
  int P1 = Pbase + 16 + m; if (P1 > 4751) P1 = 4751;
  size_t rA0 = (size_t)P0*160 + q;
  size_t rA1 = (size_t)P1*160 + q;
  const short8* gAh = (const short8*)(const void*)Fh;
  const short8* gAl = (const short8*)(const void*)Fl;
  const short8* gWh = (const short8*)(const void*)Wph;
  const short8* gWl = (const short8*)(const void*)Wpl;
  size_t sb = (size_t)(cog*4 + wv)*64 + lane;
  floatx4 acc[2][4];
  #pragma unroll
  for (int i=0;i<2;++i)
    #pragma unroll
    for (int j=0;j<4;++j) acc[i][j] = (floatx4)(0.f);
  short8 ph = gWh[sb], pw = gWl[sb];
  short8 cah0 = gAh[rA0], cal0 = gAl[rA0], cah1 = gAh[rA1], cal1 = gAl[rA1];
  for (int kb=0; kb<40; ++kb){
    __syncthreads();
    lbh[tid] = ph; lbl[tid] = pw;
    int nx = (kb+1 < 40) ? kb+1 : 39;
    ph = gWh[(size_t)nx*1024 + sb]; pw = gWl[(size_t)nx*1024 + sb];
    __syncthreads();
    short8 nah0 = gAh[rA0 + (size_t)nx*4];
    short8 nal0 = gAl[rA0 + (size_t)nx*4];
    short8 nah1 = gAh[rA1 + (size_t)nx*4];
    short8 nal1 = gAl[rA1 + (size_t)nx*4];
    #pragma unroll
    for (int nb=0; nb<4; ++nb){
      short8 bh = lbh[nb*64 + lane];
      short8 bl = lbl[nb*64 + lane];
      acc[0][nb] = __builtin_amdgcn_mfma_f32_16x16x32_bf16(cah0, bh, acc[0][nb], 0,0,0);
      acc[0][nb] = __builtin_amdgcn_mfma_f32_16x16x32_bf16(cah0, bl, acc[0][nb], 0,0,0);
      acc[0][nb] = __builtin_amdgcn_mfma_f32_16x16x32_bf16(cal0, bh, acc[0][nb], 0,0,0);
      acc[1][nb] = __builtin_amdgcn_mfma_f32_16x16x32_bf16(cah1, bh, acc[1][nb], 0,0,0);
      acc[1][nb] = __builtin_amdgcn_mfma_f32_16x16x32_bf16(cah1, bl, acc[1][nb], 0,0,0);
      acc[1][nb] = __builtin_amdgcn_mfma_f32_16x16x32_bf16(cal1, bh, acc[1][nb], 0,0,0);
    }
    cah0 = nah0; cal0 = nal0; cah1 = nah1; cal1 = nal1;
  }
  int n16 = lane & 15;
  #pragma unroll
  for (int mg=0; mg<2; ++mg){
    #pragma unroll
    for (int nb=0; nb<4; ++nb){
      int co = cog*64 + nb*16 + n16;
      float s = bns[co], bv = bnb[co];
      #pragma unroll
      for (int r=0; r<4; ++r){
        int P = Pbase + mg*16 + q*4 + r;
        if (P < 4752) out[(size_t)P*256 + co] = siluf(acc[mg][nb][r]*s + bv);
      }
    }
  }
}

// ---------- NHWC mean over 396 pixels ----------
__global__ __launch_bounds__(256) void k_meanN(
    const float* __restrict__ x1, float* __restrict__ mean)
{
  int n = blockIdx.x; int c = threadIdx.x;
  float s = 0.f;
  for (int p=0; p<396; ++p) s += x1[((size_t)n*396+p)*256 + c];
  mean[n*256+c] = s*(1.f/396.f);
}

// ---------- SE FC ----------
__global__ __launch_bounds__(256) void k_se_fc(
    const float* __restrict__ mean, const float* __restrict__ w1, const float* __restrict__ b1,
    const float* __restrict__ w2, const float* __restrict__ b2, float* __restrict__ g, int H)
{
  __shared__ float m[256];
  __shared__ float h[32];
  int n = blockIdx.x; int t = threadIdx.x;
  m[t] = mean[n*256 + t];
  __syncthreads();
  if (t < H){
    float s = b1[t];
    for (int c=0; c<256; ++c) s += m[c]*w1[t*256+c];
    h[t] = siluf(s);
  }
  __syncthreads();
  float s = b2[t];
  for (int j=0; j<H; ++j) s += h[j]*w2[t*H+j];
  g[n*256+t] = sigf(s);
}

// ---------- x1 NHWC * g -> padded [n][14][35][256] bf16 hi/lo ----------
__global__ __launch_bounds__(256) void k_topad(
    const float* __restrict__ x1, const float* __restrict__ g,
    hb* __restrict__ Xh, hb* __restrict__ Xl)
{
  int y = blockIdx.x;   // 0..13
  int n = blockIdx.y;
  int c = threadIdx.x;
  float gc = g[n*256+c];
  for (int xx=0; xx<35; ++xx){
    float v = 0.f;
    if (y>=1 && y<=12 && xx>=1 && xx<=33)
      v = x1[((size_t)n*396 + (y-1)*33 + (xx-1))*256 + c]*gc;
    hb hv, lv; split2(v, &hv, &lv);
    size_t o = (((size_t)n*14+y)*35+xx)*256 + c;
    Xh[o] = hv; Xl[o] = lv;
  }
}

// ---------- image 3x3 conv as implicit MFMA GEMM: M=4752, N=256, K=2304; out NCHW ----------
__global__ __launch_bounds__(256) void k_conv3s_mfma(
    const hb* __restrict__ Xh, const hb* __restrict__ Xl,
    const hb* __restrict__ Wph, const hb* __restrict__ Wpl,
    const float* __restrict__ bns, const float* __restrict__ bnb,
    float* __restrict__ out)
{
  __shared__ short8 lbh[256], lbl[256];
  int tid = threadIdx.x;
  int wv = tid >> 6, lane = tid & 63;
  int cog = blockIdx.y;
  int Pbase = blockIdx.x*128 + wv*32;
  int m = lane & 15, q = lane >> 4;
  int P0 = Pbase + m;      if (P0 > 4751) P0 = 4751;
  int P1 = Pbase + 16 + m; if (P1 > 4751) P1 = 4751;
  int n0 = P0/396, pim0 = P0%396;
  int n1 = P1/396, pim1 = P1%396;
  size_t base0 = (size_t)((n0*14 + pim0/33)*35 + pim0%33)*32 + q;
  size_t base1 = (size_t)((n1*14 + pim1/33)*35 + pim1%33)*32 + q;
  const short8* gAh = (const short8*)(const void*)Xh;
  const short8* gAl = (const short8*)(const void*)Xl;
  const short8* gWh = (const short8*)(const void*)Wph;
  const short8* gWl = (const short8*)(const void*)Wpl;
  size_t sb = (size_t)(cog*4 + wv)*64 + lane;
  floatx4 acc[2][4];
  #pragma unroll
  for (int i=0;i<2;++i)
    #pragma unroll
    for (int j=0;j<4;++j) acc[i][j] = (floatx4)(0.f);
  short8 ph = gWh[sb], pw = gWl[sb];
  short8 cah0 = gAh[base0], cal0 = gAl[base0], cah1 = gAh[base1], cal1 = gAl[base1];
  for (int idx=0; idx<72; ++idx){
    __syncthreads();
    lbh[tid] = ph; lbl[tid] = pw;
    int nx = (idx+1 < 72) ? idx+1 : 71;
    ph = gWh[(size_t)nx*1024 + sb]; pw = gWl[(size_t)nx*1024 + sb];
    __syncthreads();
    int tap = nx >> 3, kb = nx & 7;
    int dy = (tap*11) >> 5;            // tap/3
    int dx = tap - dy*3;
    int ao = (dy*35+dx)*32 + kb*4;
    short8 nah0 = gAh[base0 + ao];
    short8 nal0 = gAl[base0 + ao];
    short8 nah1 = gAh[base1 + ao];
    short8 nal1 = gAl[base1 + ao];
    #pragma unroll
    for (int nb=0; nb<4; ++nb){
      short8 bh = lbh[nb*64 + lane];
      short8 bl = lbl[nb*64 + lane];
      acc[0][nb] = __builtin_amdgcn_mfma_f32_16x16x32_bf16(cah0, bh, acc[0][nb], 0,0,0);
      acc[0][nb] = __builtin_amdgcn_mfma_f32_16x16x32_bf16(cah0, bl, acc[0][nb], 0,0,0);
      acc[0][nb] = __builtin_amdgcn_mfma_f32_16x16x32_bf16(cal0, bh, acc[0][nb], 0,0,0);
      acc[1][nb] = __builtin_amdgcn_mfma_f32_16x16x32_bf16(cah1, bh, acc[1][nb], 0,0,0);
      acc[1][nb] = __builtin_amdgcn_mfma_f32_16x16x32_bf16(cah1, bl, acc[1][nb], 0,0,0);
      acc[1][nb] = __builtin_amdgcn_mfma_f32_16x16x32_bf16(cal1, bh, acc[1][nb], 0,0,0);
    }
    cah0 = nah0; cal0 = nal0; cah1 = nah1; cal1 = nal1;
  }
  int n16 = lane & 15;
  #pragma unroll
  for (int mg=0; mg<2; ++mg){
    #pragma unroll
    for (int r=0; r<4; ++r){
      int P = Pbase + mg*16 + q*4 + r;
      if (P < 4752){
        int nn = P/396, pim = P%396;
        #pragma unroll
        for (int nb=0; nb<4; ++nb){
          int co = cog*64 + nb*16 + n16;
          out[((size_t)nn*256+co)*396 + pim] = siluf(acc[mg][nb][r]*bns[co] + bnb[co]);
        }
      }
    }
  }
}

// ---------- heads: depth (40, NCHW) and ctx (64, NHWC) ----------
__global__ __launch_bounds__(256) void k_heads(
    const float* __restrict__ x, const float* __restrict__ dhw, const float* __restrict__ dhb,
    const float* __restrict__ chw, const float* __restrict__ chb,
    float* __restrict__ dep, float* __restrict__ ctx2)
{
  int p = blockIdx.x*256 + threadIdx.x;
  int co = blockIdx.y; int n = blockIdx.z;
  if (p >= 396) return;
  const float* xb = x + (size_t)n*256*396 + p;
  const float* w = (co < 40) ? (dhw + (size_t)co*256) : (chw + (size_t)(co-40)*256);
  float acc = 0.f;
  for (int ci=0; ci<256; ++ci) acc += xb[(size_t)ci*396] * w[ci];
  if (co < 40) dep[((size_t)n*40+co)*396 + p] = acc + dhb[co];
  else { int c = co-40; ctx2[((size_t)n*396+p)*64 + c] = acc + chb[c]; }
}

// ---------- softmax over 40 depth channels ----------
__global__ __launch_bounds__(256) void k_softmax40(float* __restrict__ dep)
{
  int i = blockIdx.x*256 + threadIdx.x;
  if (i >= 12*396) return;
  int n = i/396, p = i%396;
  float* base = dep + (size_t)n*40*396 + p;
  float mx = -1e30f;
  for (int d=0; d<40; ++d) mx = fmaxf(mx, base[(size_t)d*396]);
  float s = 0.f;
  for (int d=0; d<40; ++d){ float e = expf(base[(size_t)d*396]-mx); base[(size_t)d*396]=e; s+=e; }
  float inv = 1.f/s;
  for (int d=0; d<40; ++d) base[(size_t)d*396] *= inv;
}

// ---------- geometry + count (fused) ----------
__global__ __launch_bounds__(256) void k_geom(
    const float* __restrict__ rots, const float* __restrict__ trans,
    const float* __restrict__ intr, int* __restrict__ vox, int* __restrict__ cnt)
{
  int pt = blockIdx.x*256 + threadIdx.x;
  if (pt >= 190080) return;
  int b = pt/95040; int r = pt%95040;
  int n = r/15840;  int r2 = r%15840;
  int d = r2/396;   int pim = r2%396;
  int y = pim/33, x = pim%33;
  int bn = b*6+n;
  const float* R = rots + (size_t)bn*9;
  const float* T = trans + (size_t)bn*3;
  const float* K = intr + (size_t)bn*9;
  float fx=K[0], cx=K[2], fy=K[4], cy=K[5];
  float xs = (float)x * 32.96875f;
  float ys = (float)((double)y * (383.0/11.0));
  float dv = 4.0f + (float)d;
  float camx = (xs-cx)*dv/fx;
  float camy = (ys-cy)*dv/fy;
  float gx = R[0]*camx + R[1]*camy + R[2]*dv + T[0];
  float gy = R[3]*camx + R[4]*camy + R[5]*dv + T[1];
  float gz = R[6]*camx + R[7]*camy + R[8]*dv + T[2];
  int ix = (int)floorf(gx + 50.f);
  int iy = (int)floorf(gy + 50.f);
  int iz = (int)floorf((gz + 10.f)/5.f);
  bool valid = (ix>=0 && ix<100 && iy>=0 && iy<100 && iz>=0 && iz<4);
  int sid = iz*10000 + ix*100 + iy;
  vox[pt] = valid ? sid : -1;
  if (valid) atomicAdd(&cnt[b*40000 + sid], 1);
}

// ---------- scan ----------
__global__ __launch_bounds__(256) void k_scan1(
    const int* __restrict__ cnt, int* __restrict__ off, int* __restrict__ bsum)
{
  __shared__ int s[256];
  int t = threadIdx.x;
  int i = blockIdx.x*256 + t;
  int v = (i < 80000) ? cnt[i] : 0;
  s[t] = v; __syncthreads();
  for (int o=1;o<256;o<<=1){
    int x = (t>=o) ? s[t-o] : 0;
    __syncthreads();
    s[t] += x;
    __syncthreads();
  }
  if (i < 80000) off[i] = s[t] - v;
  if (t == 255) bsum[blockIdx.x] = s[255];
}

__global__ void k_scan2(int* __restrict__ bsum, int nblk)
{
  if (threadIdx.x==0 && blockIdx.x==0){
    int run = 0;
    for (int j=0;j<nblk;++j){ int t = bsum[j]; bsum[j] = run; run += t; }
  }
}

__global__ __launch_bounds__(256) void k_scan3(
    int* __restrict__ off, const int* __restrict__ bsum, int* __restrict__ cur)
{
  int i = blockIdx.x*256 + threadIdx.x;
  if (i >= 80000) return;
  int o = off[i] + bsum[i>>8];
  off[i] = o;
  cur[i] = o;
}

__global__ __launch_bounds__(256) void k_fill(
    const int* __restrict__ vox, int* __restrict__ cur, int* __restrict__ list)
{
  int pt = blockIdx.x*256 + threadIdx.x;
  if (pt >= 190080) return;
  int s = vox[pt];
  if (s < 0) return;
  int b = pt/95040;
  int slot = atomicAdd(&cur[b*40000 + s], 1);
  list[slot] = pt;
}

// ---------- gather: one wave per (b,sid), lane=channel ----------
__global__ __launch_bounds__(256) void k_gather(
    const int* __restrict__ off, const int* __restrict__ cnt, const int* __restrict__ list,
    const float* __restrict__ ctx2, const float* __restrict__ dep, float* __restrict__ bev)
{
  int tid = threadIdx.x;
  int bv = blockIdx.x*4 + (tid>>6);
  int c = tid & 63;
  int b = bv/40000, sid = bv%40000;
  int st = off[bv], nn = cnt[bv];
  float s = 0.f;
  for (int k=0;k<nn;++k){
    int pt = list[st+k];
    int r = pt%95040;
    int bn = b*6 + r/15840;
    int r2 = r%15840;
    int dd = r2/396, pim = r2%396;
    s += ctx2[((size_t)bn*396+pim)*64 + c] * dep[((size_t)bn*40+dd)*396 + pim];
  }
  int iz = sid/10000, rem = sid%10000;
  bev[(size_t)b*2560000 + (size_t)iz*640000 + (size_t)c*10000 + rem] = s;
}

// ---------- NCHW fp32 (*g) -> padded NHWC bf16 hi/lo [b][102][102][256] ----------
__global__ __launch_bounds__(256) void k_tohwc(
    const float* __restrict__ in, hb* __restrict__ Ah, hb* __restrict__ Al,
    const float* __restrict__ g)
{
  int y = blockIdx.x;      // 0..101
  int b = blockIdx.y;
  int ci = threadIdx.x;
  float gc = g ? g[(size_t)b*256 + ci] : 1.f;
  for (int x=0; x<102; ++x){
    float v = 0.f;
    if (y>=1 && y<=100 && x>=1 && x<=100)
      v = in[(((size_t)b*256 + ci)*100 + (y-1))*100 + (x-1)] * gc;
    hb hv, lv; split2(v, &hv, &lv);
    size_t o = (((size_t)b*102 + y)*102 + x)*256 + ci;
    Ah[o] = hv; Al[o] = lv;
  }
}

// ---------- row mean (NCHW rows) ----------
__global__ __launch_bounds__(256) void k_rowmean(
    const float* __restrict__ in, float* __restrict__ out, int rowlen, float inv)
{
  __shared__ float ws[4];
  int row = blockIdx.x; int t = threadIdx.x;
  const float* p = in + (size_t)row*rowlen;
  float s = 0.f;
  for (int i=t; i<rowlen; i+=256) s += p[i];
  #pragma unroll
  for (int off=32; off; off>>=1) s += __shfl_down(s, off);
  if ((t&63)==0) ws[t>>6] = s;
  __syncthreads();
  if (t==0) out[row] = (ws[0]+ws[1]+ws[2]+ws[3]) * inv;
}

// ---------- BEV MFMA conv ----------
__device__ __forceinline__ void a_addrs(int idx, int bb, int x0, int y0, int m, int q,
                                        size_t* o0, size_t* o1)
{
  int tap = idx >> 3, kb = idx & 7;
  int dy = (tap*11) >> 5;
  int dx = tap - dy*3;
  int xA = x0 + dx + m; xA = xA > 101 ? 101 : xA;
  int yA0 = y0 + dy;     yA0 = yA0 > 101 ? 101 : yA0;
  int yA1 = y0 + 4 + dy; yA1 = yA1 > 101 ? 101 : yA1;
  *o0 = (size_t)((bb*102 + yA0)*102 + xA)*32 + kb*4 + q;
  *o1 = (size_t)((bb*102 + yA1)*102 + xA)*32 + kb*4 + q;
}

__global__ __launch_bounds__(256) void k_conv3_mfma(
    const hb* __restrict__ Ah, const hb* __restrict__ Al,
    const hb* __restrict__ Wph, const hb* __restrict__ Wpl,
    const float* __restrict__ bns, const float* __restrict__ bnb,
    const float* __restrict__ res, float* __restrict__ out, int Cout)
{
  __shared__ short8 lbh[256], lbl[256];
  const int NB = Cout >> 4;
  int tid = threadIdx.x;
  int wv = tid >> 6, lane = tid & 63;
  int xg = blockIdx.x % 7, yg = blockIdx.x / 7;
  int cog = blockIdx.y, bb = blockIdx.z;
  int x0 = xg*16;
  int y0 = yg*8 + wv;
  int m = lane & 15, q = lane >> 4;
  int nb0 = cog*4;
  floatx4 acc[2][4];
  #pragma unroll
  for (int i=0;i<2;++i)
    #pragma unroll
    for (int j=0;j<4;++j) acc[i][j] = (floatx4)(0.f);

  const short8* gAh = (const short8*)(const void*)Ah;
  const short8* gAl = (const short8*)(const void*)Al;
  const short8* gWh = (const short8*)(const void*)Wph;
  const short8* gWl = (const short8*)(const void*)Wpl;
  const size_t nbstride = (size_t)NB*64;
  const size_t sb = (size_t)(nb0 + wv)*64 + lane;

  size_t o0,o1;
  a_addrs(0, bb, x0, y0, m, q, &o0, &o1);
  short8 cah0 = gAh[o0], cal0 = gAl[o0], cah1 = gAh[o1], cal1 = gAl[o1];
  short8 ph = gWh[sb], pl = gWl[sb];

  for (int idx=0; idx<72; ++idx){
    __syncthreads();
    lbh[tid] = ph;
    lbl[tid] = pl;
    int nx = (idx+1 < 72) ? idx+1 : 71;
    ph = gWh[(size_t)nx*nbstride + sb];
    pl = gWl[(size_t)nx*nbstride + sb];
    __syncthreads();
    size_t n0,n1;
    a_addrs(nx, bb, x0, y0, m, q, &n0, &n1);
    short8 nah0 = gAh[n0], nal0 = gAl[n0], nah1 = gAh[n1], nal1 = gAl[n1];
    #pragma unroll
    for (int nb=0; nb<4; ++nb){
      short8 bh = lbh[nb*64 + lane];
      short8 bl = lbl[nb*64 + lane];
      acc[0][nb] = __builtin_amdgcn_mfma_f32_16x16x32_bf16(cah0, bh, acc[0][nb], 0,0,0);
      acc[0][nb] = __builtin_amdgcn_mfma_f32_16x16x32_bf16(cah0, bl, acc[0][nb], 0,0,0);
      acc[0][nb] = __builtin_amdgcn_mfma_f32_16x16x32_bf16(cal0, bh, acc[0][nb], 0,0,0);
      acc[1][nb] = __builtin_amdgcn_mfma_f32_16x16x32_bf16(cah1, bh, acc[1][nb], 0,0,0);
      acc[1][nb] = __builtin_amdgcn_mfma_f32_16x16x32_bf16(cah1, bl, acc[1][nb], 0,0,0);
      acc[1][nb] = __builtin_amdgcn_mfma_f32_16x16x32_bf16(cal1, bh, acc[1][nb], 0,0,0);
    }
    cah0 = nah0; cal0 = nal0; cah1 = nah1; cal1 = nal1;
  }

  int n = lane & 15;
  int xq = x0 + q*4;
  #pragma unroll
  for (int mg=0; mg<2; ++mg){
    int yo = y0 + mg*4;
    if (yo < 100 && xq < 100){
      #pragma unroll
      for (int nb=0; nb<4; ++nb){
        int co = cog*64 + nb*16 + n;
        float s = bns[co], bv = bnb[co];
        floatx4 a = acc[mg][nb];
        float4 v;
        v.x = fmaxf(a[0]*s+bv, 0.f);
        v.y = fmaxf(a[1]*s+bv, 0.f);
        v.z = fmaxf(a[2]*s+bv, 0.f);
        v.w = fmaxf(a[3]*s+bv, 0.f);
        size_t o = ((size_t)(bb*Cout+co)*100 + yo)*100 + xq;
        if (res){
          float4 rv = *(const float4*)(res + o);
          v.x += rv.x; v.y += rv.y; v.z += rv.z; v.w += rv.w;
        }
        *(float4*)(out + o) = v;
      }
    }
  }
}

// ---------- final 1x1 conv 128->16 ----------
__global__ __launch_bounds__(256) void k_final(
    const float* __restrict__ h, const float* __restrict__ W, const float* __restrict__ bias,
    float* __restrict__ out)
{
  int pix = blockIdx.x*256 + threadIdx.x;
  int oc = blockIdx.y, b = blockIdx.z;
  if (pix >= 10000) return;
  const float* hb_ = h + (size_t)b*128*10000 + pix;
  const float* w = W + (size_t)oc*128;
  float acc = bias[oc];
  for (int ci=0; ci<128; ++ci) acc += hb_[(size_t)ci*10000]*w[ci];
  out[((size_t)(b*16+oc))*10000 + pix] = acc;
}

extern "C" void kernel_launch(void* const* d_in, const int* in_sizes, int n_in,
                              void* d_out, int out_size, void* d_ws, size_t ws_size,
                              hipStream_t stream)
{
  (void)in_sizes; (void)n_in; (void)out_size; (void)ws_size;
  const float* feats = (const float*)d_in[0];
  const float* rots  = (const float*)d_in[1];
  const float* trans = (const float*)d_in[2];
  const float* intr  = (const float*)d_in[3];
  const float* nw1   = (const float*)d_in[4];
  const float* bn1s  = (const float*)d_in[5];
  const float* bn1b  = (const float*)d_in[6];
  const float* se1w1 = (const float*)d_in[7];
  const float* se1b1 = (const float*)d_in[8];
  const float* se1w2 = (const float*)d_in[9];
  const float* se1b2 = (const float*)d_in[10];
  const float* nw2   = (const float*)d_in[11];
  const float* bn2s  = (const float*)d_in[12];
  const float* bn2b  = (const float*)d_in[13];
  const float* dhw   = (const float*)d_in[14];
  const float* dhb   = (const float*)d_in[15];
  const float* chw   = (const float*)d_in[16];
  const float* chb   = (const float*)d_in[17];
  const float* bcw1  = (const float*)d_in[18];
  const float* bcs1  = (const float*)d_in[19];
  const float* bcb1  = (const float*)d_in[20];
  const float* bcsw1 = (const float*)d_in[21];
  const float* bcsb1 = (const float*)d_in[22];
  const float* bcsw2 = (const float*)d_in[23];
  const float* bcsb2 = (const float*)d_in[24];
  const float* bcw2  = (const float*)d_in[25];
  const float* bcs2  = (const float*)d_in[26];
  const float* bcb2  = (const float*)d_in[27];
  const float* dw1   = (const float*)d_in[28];
  const float* ds1   = (const float*)d_in[29];
  const float* db1   = (const float*)d_in[30];
  const float* dw2   = (const float*)d_in[31];
  const float* db2   = (const float*)d_in[32];
  float* out = (float*)d_out;

  // ---- workspace layout (float units) ----
  float* ws = (float*)d_ws;
  float* bev   = ws;                       // S0: 5,120,000
  float* h1    = ws + 5120000;             // S1: 5,120,000
  hb*    Ah    = (hb*)(ws + 10240000);     // S2: 2,663,424 fu
  hb*    Al    = (hb*)(ws + 12903424);     // S3: 2,663,424 fu
  float* x2    = ws + 15566848;            // S4: 1,216,512
  float* S5    = ws + 16783360;            // 589,824
  float* dep   = ws + 17373184;            // 190,080
  float* ctx2  = ws + 17563264;            // 304,128
  float* mean1 = ws + 17867392;            // 3072
  float* g1    = mean1 + 3072;
  float* mean2 = g1 + 3072;
  float* g2    = mean2 + 512;
  int*   vox   = (int*)(ws + 17875584);    // 190,080 ints
  // phase aliases
  hb* Fh   = (hb*)bev;                     // 3,041,280 fu
  hb* Wc1h = (hb*)(bev + 3041280);         // 163,840 fu (327,680 bf16)
  hb* Wc1l = (hb*)(bev + 3205120);         // 163,840 fu  (FIXED: was +81920)
  float* x1 = h1;                          // NHWC conv1 out (1,216,512 fu)
  hb* Fl   = (hb*)(h1 + 1216512);          // 3,041,280 fu
  hb* Xh   = (hb*)Ah;                      // padded image tile
  hb* Xl   = (hb*)Al;
  hb* Wc2h = (hb*)S5;                      // 294,912 fu
  hb* Wc2l = (hb*)(S5 + 294912);           // 294,912 fu
  int* cnt  = (int*)h1;                    // splat arrays (x1/Fl dead by then)
  int* off  = cnt + 80000;
  int* cur  = off + 80000;
  int* bsum = cur + 80000;
  int* list = bsum + 1024;
  float* h3 = h1;
  hb* Wp1h = (hb*)x2;                      // BEV conv weights (x2 dead after heads)
  hb* Wp1l = (hb*)(x2 + 294912);
  hb* Wp3h = (hb*)(x2 + 589824);
  hb* Wp3l = (hb*)(x2 + 589824 + 147456);
  hb* Wp2h = (hb*)S5;                      // Wc2 dead after conv3s
  hb* Wp2l = (hb*)(S5 + 294912);

  // ---- image branch (MFMA) ----
  k_trans_feats<<<dim3(7,12),256,0,stream>>>(feats,Fh,Fl);
  k_wpack1<<<1280,256,0,stream>>>(nw1,Wc1h,Wc1l);
  k_mfma_gemm1<<<dim3(38,4),256,0,stream>>>(Fh,Fl,Wc1h,Wc1l,bn1s,bn1b,x1);
  k_meanN<<<12,256,0,stream>>>(x1,mean1);
  k_se_fc<<<12,256,0,stream>>>(mean1,se1w1,se1b1,se1w2,se1b2,g1,32);
  k_topad<<<dim3(14,12),256,0,stream>>>(x1,g1,Xh,Xl);
  k_wpack<<<(589824+255)/256,256,0,stream>>>(nw2,Wc2h,Wc2l,16);
  k_conv3s_mfma<<<dim3(38,4),256,0,stream>>>(Xh,Xl,Wc2h,Wc2l,bn2s,bn2b,x2);
  k_heads<<<dim3(2,104,12),256,0,stream>>>(x2,dhw,dhb,chw,chb,dep,ctx2);
  k_softmax40<<<(4752+255)/256,256,0,stream>>>(dep);

  // ---- pack BEV conv weights (x2, Wc2 dead now) ----
  k_wpack<<<(589824+255)/256,256,0,stream>>>(bcw1,Wp1h,Wp1l,16);
  k_wpack<<<(589824+255)/256,256,0,stream>>>(bcw2,Wp2h,Wp2l,16);
  k_wpack<<<(294912+255)/256,256,0,stream>>>(dw1,Wp3h,Wp3l,8);

  // ---- lift-splat (gather form) ----
  hipMemsetAsync(cnt, 0, 80000*sizeof(int), stream);
  k_geom<<<(190080+255)/256,256,0,stream>>>(rots,trans,intr,vox,cnt);
  k_scan1<<<313,256,0,stream>>>(cnt,off,bsum);
  k_scan2<<<1,64,0,stream>>>(bsum,313);
  k_scan3<<<(80000+255)/256,256,0,stream>>>(off,bsum,cur);
  k_fill<<<(190080+255)/256,256,0,stream>>>(vox,cur,list);
  k_gather<<<20000,256,0,stream>>>(off,cnt,list,ctx2,dep,bev);

  // ---- BEV encoder (MFMA convs) ----
  k_tohwc<<<dim3(102,2),256,0,stream>>>(bev,Ah,Al,nullptr);
  k_conv3_mfma<<<dim3(91,4,2),256,0,stream>>>(Ah,Al,Wp1h,Wp1l,bcs1,bcb1,nullptr,h1,256);
  k_rowmean<<<512,256,0,stream>>>(h1,mean2,10000,1e-4f);
  k_se_fc<<<2,256,0,stream>>>(mean2,bcsw1,bcsb1,bcsw2,bcsb2,g2,16);
  k_tohwc<<<dim3(102,2),256,0,stream>>>(h1,Ah,Al,g2);   // SE scale fused
  k_conv3_mfma<<<dim3(91,4,2),256,0,stream>>>(Ah,Al,Wp2h,Wp2l,bcs2,bcb2,bev,bev,256);
  k_tohwc<<<dim3(102,2),256,0,stream>>>(bev,Ah,Al,nullptr);
  k_conv3_mfma<<<dim3(91,2,2),256,0,stream>>>(Ah,Al,Wp3h,Wp3l,ds1,db1,nullptr,h3,128);
  k_final<<<dim3(40,16,2),256,0,stream>>>(h3,dw2,db2,out);
}

// Round 7
// 784.513 us; speedup vs baseline: 11.9483x; 1.2570x over previous
//
#include <hip/hip_runtime.h>
#include <hip/hip_bf16.h>
#include <cmath>

// LSS pipeline R7: BEV MFMA conv with LDS A-staging (kills 443MB L2-miss
// traffic), kb-major weight pack, XCD-swizzled flat grid; coalesced tohwc.

typedef __attribute__((ext_vector_type(8))) short short8;
typedef __attribute__((ext_vector_type(4))) float floatx4;
typedef __hip_bfloat16 hb;

__device__ __forceinline__ float sigf(float x){ return 1.0f/(1.0f+expf(-x)); }
__device__ __forceinline__ float siluf(float x){ return x*sigf(x); }
__device__ __forceinline__ void split2(float v, hb* h, hb* l){
  hb hv = __float2bfloat16(v);
  *h = hv; *l = __float2bfloat16(v - __bfloat162float(hv));
}

// ---------- feats NCHW -> NHWC bf16 hi/lo [n][396][1280] ----------
__global__ __launch_bounds__(256) void k_trans_feats(
    const float* __restrict__ feats, hb* __restrict__ Fh, hb* __restrict__ Fl)
{
  __shared__ float tile[64][65];
  int n = blockIdx.y;
  int p0 = blockIdx.x*64;
  int tid = threadIdx.x;
  int tr = tid >> 6;      // 0..3
  int tc = tid & 63;
  for (int c0=0; c0<1280; c0+=64){
    __syncthreads();
    #pragma unroll
    for (int it=0; it<16; ++it){
      int ci = c0 + it*4 + tr;
      int p = p0 + tc;
      float v = 0.f;
      if (p < 396) v = feats[((size_t)n*1280 + ci)*396 + p];
      tile[it*4+tr][tc] = v;
    }
    __syncthreads();
    #pragma unroll
    for (int it=0; it<16; ++it){
      int pl = it*4 + tr;
      int p = p0 + pl;
      if (p < 396){
        hb hv, lv; split2(tile[tc][pl], &hv, &lv);
        size_t o = ((size_t)n*396 + p)*1280 + c0 + tc;
        Fh[o] = hv; Fl[o] = lv;
      }
    }
  }
}

// ---------- pack 1x1 weights [256][1280] -> [(kb*16+nb)*64+lane][8] ----------
__global__ __launch_bounds__(256) void k_wpack1(
    const float* __restrict__ W, hb* __restrict__ Wph, hb* __restrict__ Wpl)
{
  int i = blockIdx.x*256 + threadIdx.x;
  if (i >= 40*16*512) return;
  int j = i & 7;
  int lane = (i>>3) & 63;
  int t2 = i >> 9;
  int nb = t2 & 15;
  int kb = t2 >> 4;
  int ci = kb*32 + (lane>>4)*8 + j;
  int co = nb*16 + (lane&15);
  hb hv, lv; split2(W[(size_t)co*1280 + ci], &hv, &lv);
  Wph[i] = hv; Wpl[i] = lv;
}

// ---------- pack 3x3 weights tap-major (image conv): [((tap*8+kb)*NB+nb)*64+lane][8] ----------
__global__ __launch_bounds__(256) void k_wpack(
    const float* __restrict__ W, hb* __restrict__ Wph, hb* __restrict__ Wpl, int NB)
{
  int i = blockIdx.x*256 + threadIdx.x;
  int total = 9*8*NB*512;
  if (i >= total) return;
  int j = i & 7;
  int t1 = i >> 3;
  int lane = t1 & 63;
  int t2 = t1 >> 6;
  int nb = t2 % NB;
  int t3 = t2 / NB;
  int kb = t3 & 7;
  int tap = t3 >> 3;
  int ci = kb*32 + (lane>>4)*8 + j;
  int co = nb*16 + (lane&15);
  hb hv, lv; split2(W[(size_t)co*2304 + ci*9 + tap], &hv, &lv);
  Wph[i] = hv; Wpl[i] = lv;
}

// ---------- pack 3x3 weights kb-major (BEV conv): [((kb*9+tap)*NB+nb)*64+lane][8] ----------
__global__ __launch_bounds__(256) void k_wpackT(
    const float* __restrict__ W, hb* __restrict__ Wph, hb* __restrict__ Wpl, int NB)
{
  int i = blockIdx.x*256 + threadIdx.x;
  int total = 9*8*NB*512;
  if (i >= total) return;
  int j = i & 7;
  int t1 = i >> 3;
  int lane = t1 & 63;
  int t2 = t1 >> 6;
  int nb = t2 % NB;
  int t3 = t2 / NB;
  int tap = t3 % 9;
  int kb = t3 / 9;
  int ci = kb*32 + (lane>>4)*8 + j;
  int co = nb*16 + (lane&15);
  hb hv, lv; split2(W[(size_t)co*2304 + ci*9 + tap], &hv, &lv);
  Wph[i] = hv; Wpl[i] = lv;
}

// ---------- conv1 as MFMA GEMM: M=4752, N=256, K=1280; BN+SiLU; out NHWC ----------
__global__ __launch_bounds__(256) void k_mfma_gemm1(
    const hb* __restrict__ Fh, const hb* __restrict__ Fl,
    const hb* __restrict__ Wph, const hb* __restrict__ Wpl,
    const float* __restrict__ bns, const float* __restrict__ bnb,
    float* __restrict__ out)
{
  __shared__ short8 lbh[256], lbl[256];
  int tid = threadIdx.x;
  int wv = tid >> 6, lane = tid & 63;
  int cog = blockIdx.y;
  int Pbase = blockIdx.x*128 + wv*32;
  int m = lane & 15, q = lane >> 4;
  int P0 = Pbase + m;      if (P0 > 4751) P0 = 4751;
  int P1 = Pbase + 16 + m; if (P1 > 4751) P1 = 4751;
  size_t rA0 = (size_t)P0*160 + q;
  size_t rA1 = (size_t)P1*160 + q;
  const short8* gAh = (const short8*)(const void*)Fh;
  const short8* gAl = (const short8*)(const void*)Fl;
  const short8* gWh = (const short8*)(const void*)Wph;
  const short8* gWl = (const short8*)(const void*)Wpl;
  size_t sb = (size_t)(cog*4 + wv)*64 + lane;
  floatx4 acc[2][4];
  #pragma unroll
  for (int i=0;i<2;++i)
    #pragma unroll
    for (int j=0;j<4;++j) acc[i][j] = (floatx4)(0.f);
  short8 ph = gWh[sb], pw = gWl[sb];
  short8 cah0 = gAh[rA0], cal0 = gAl[rA0], cah1 = gAh[rA1], cal1 = gAl[rA1];
  for (int kb=0; kb<40; ++kb){
    __syncthreads();
    lbh[tid] = ph; lbl[tid] = pw;
    int nx = (kb+1 < 40) ? kb+1 : 39;
    ph = gWh[(size_t)nx*1024 + sb]; pw = gWl[(size_t)nx*1024 + sb];
    __syncthreads();
    short8 nah0 = gAh[rA0 + (size_t)nx*4];
    short8 nal0 = gAl[rA0 + (size_t)nx*4];
    short8 nah1 = gAh[rA1 + (size_t)nx*4];
    short8 nal1 = gAl[rA1 + (size_t)nx*4];
    #pragma unroll
    for (int nb=0; nb<4; ++nb){
      short8 bh = lbh[nb*64 + lane];
      short8 bl = lbl[nb*64 + lane];
      acc[0][nb] = __builtin_amdgcn_mfma_f32_16x16x32_bf16(cah0, bh, acc[0][nb], 0,0,0);
      acc[0][nb] = __builtin_amdgcn_mfma_f32_16x16x32_bf16(cah0, bl, acc[0][nb], 0,0,0);
      acc[0][nb] = __builtin_amdgcn_mfma_f32_16x16x32_bf16(cal0, bh, acc[0][nb], 0,0,0);
      acc[1][nb] = __builtin_amdgcn_mfma_f32_16x16x32_bf16(cah1, bh, acc[1][nb], 0,0,0);
      acc[1][nb] = __builtin_amdgcn_mfma_f32_16x16x32_bf16(cah1, bl, acc[1][nb], 0,0,0);
      acc[1][nb] = __builtin_amdgcn_mfma_f32_16x16x32_bf16(cal1, bh, acc[1][nb], 0,0,0);
    }
    cah0 = nah0; cal0 = nal0; cah1 = nah1; cal1 = nal1;
  }
  int n16 = lane & 15;
  #pragma unroll
  for (int mg=0; mg<2; ++mg){
    #pragma unroll
    for (int nb=0; nb<4; ++nb){
      int co = cog*64 + nb*16 + n16;
      float s = bns[co], bv = bnb[co];
      #pragma unroll
      for (int r=0; r<4; ++r){
        int P = Pbase + mg*16 + q*4 + r;
        if (P < 4752) out[(size_t)P*256 + co] = siluf(acc[mg][nb][r]*s + bv);
      }
    }
  }
}

// ---------- NHWC mean over 396 pixels ----------
__global__ __launch_bounds__(256) void k_meanN(
    const float* __restrict__ x1, float* __restrict__ mean)
{
  int n = blockIdx.x; int c = threadIdx.x;
  float s = 0.f;
  for (int p=0; p<396; ++p) s += x1[((size_t)n*396+p)*256 + c];
  mean[n*256+c] = s*(1.f/396.f);
}

// ---------- SE FC ----------
__global__ __launch_bounds__(256) void k_se_fc(
    const float* __restrict__ mean, const float* __restrict__ w1, const float* __restrict__ b1,
    const float* __restrict__ w2, const float* __restrict__ b2, float* __restrict__ g, int H)
{
  __shared__ float m[256];
  __shared__ float h[32];
  int n = blockIdx.x; int t = threadIdx.x;
  m[t] = mean[n*256 + t];
  __syncthreads();
  if (t < H){
    float s = b1[t];
    for (int c=0; c<256; ++c) s += m[c]*w1[t*256+c];
    h[t] = siluf(s);
  }
  __syncthreads();
  float s = b2[t];
  for (int j=0; j<H; ++j) s += h[j]*w2[t*H+j];
  g[n*256+t] = sigf(s);
}

// ---------- x1 NHWC * g -> padded [n][14][35][256] bf16 hi/lo ----------
__global__ __launch_bounds__(256) void k_topad(
    const float* __restrict__ x1, const float* __restrict__ g,
    hb* __restrict__ Xh, hb* __restrict__ Xl)
{
  int y = blockIdx.x;   // 0..13
  int n = blockIdx.y;
  int c = threadIdx.x;
  float gc = g[n*256+c];
  for (int xx=0; xx<35; ++xx){
    float v = 0.f;
    if (y>=1 && y<=12 && xx>=1 && xx<=33)
      v = x1[((size_t)n*396 + (y-1)*33 + (xx-1))*256 + c]*gc;
    hb hv, lv; split2(v, &hv, &lv);
    size_t o = (((size_t)n*14+y)*35+xx)*256 + c;
    Xh[o] = hv; Xl[o] = lv;
  }
}

// ---------- image 3x3 conv as implicit MFMA GEMM: M=4752, N=256, K=2304; out NCHW ----------
__global__ __launch_bounds__(256) void k_conv3s_mfma(
    const hb* __restrict__ Xh, const hb* __restrict__ Xl,
    const hb* __restrict__ Wph, const hb* __restrict__ Wpl,
    const float* __restrict__ bns, const float* __restrict__ bnb,
    float* __restrict__ out)
{
  __shared__ short8 lbh[256], lbl[256];
  int tid = threadIdx.x;
  int wv = tid >> 6, lane = tid & 63;
  int cog = blockIdx.y;
  int Pbase = blockIdx.x*128 + wv*32;
  int m = lane & 15, q = lane >> 4;
  int P0 = Pbase + m;      if (P0 > 4751) P0 = 4751;
  int P1 = Pbase + 16 + m; if (P1 > 4751) P1 = 4751;
  int n0 = P0/396, pim0 = P0%396;
  int n1 = P1/396, pim1 = P1%396;
  size_t base0 = (size_t)((n0*14 + pim0/33)*35 + pim0%33)*32 + q;
  size_t base1 = (size_t)((n1*14 + pim1/33)*35 + pim1%33)*32 + q;
  const short8* gAh = (const short8*)(const void*)Xh;
  const short8* gAl = (const short8*)(const void*)Xl;
  const short8* gWh = (const short8*)(const void*)Wph;
  const short8* gWl = (const short8*)(const void*)Wpl;
  size_t sb = (size_t)(cog*4 + wv)*64 + lane;
  floatx4 acc[2][4];
  #pragma unroll
  for (int i=0;i<2;++i)
    #pragma unroll
    for (int j=0;j<4;++j) acc[i][j] = (floatx4)(0.f);
  short8 ph = gWh[sb], pw = gWl[sb];
  short8 cah0 = gAh[base0], cal0 = gAl[base0], cah1 = gAh[base1], cal1 = gAl[base1];
  for (int idx=0; idx<72; ++idx){
    __syncthreads();
    lbh[tid] = ph; lbl[tid] = pw;
    int nx = (idx+1 < 72) ? idx+1 : 71;
    ph = gWh[(size_t)nx*1024 + sb]; pw = gWl[(size_t)nx*1024 + sb];
    __syncthreads();
    int tap = nx >> 3, kb = nx & 7;
    int dy = (tap*11) >> 5;            // tap/3
    int dx = tap - dy*3;
    int ao = (dy*35+dx)*32 + kb*4;
    short8 nah0 = gAh[base0 + ao];
    short8 nal0 = gAl[base0 + ao];
    short8 nah1 = gAh[base1 + ao];
    short8 nal1 = gAl[base1 + ao];
    #pragma unroll
    for (int nb=0; nb<4; ++nb){
      short8 bh = lbh[nb*64 + lane];
      short8 bl = lbl[nb*64 + lane];
      acc[0][nb] = __builtin_amdgcn_mfma_f32_16x16x32_bf16(cah0, bh, acc[0][nb], 0,0,0);
      acc[0][nb] = __builtin_amdgcn_mfma_f32_16x16x32_bf16(cah0, bl, acc[0][nb], 0,0,0);
      acc[0][nb] = __builtin_amdgcn_mfma_f32_16x16x32_bf16(cal0, bh, acc[0][nb], 0,0,0);
      acc[1][nb] = __builtin_amdgcn_mfma_f32_16x16x32_bf16(cah1, bh, acc[1][nb], 0,0,0);
      acc[1][nb] = __builtin_amdgcn_mfma_f32_16x16x32_bf16(cah1, bl, acc[1][nb], 0,0,0);
      acc[1][nb] = __builtin_amdgcn_mfma_f32_16x16x32_bf16(cal1, bh, acc[1][nb], 0,0,0);
    }
    cah0 = nah0; cal0 = nal0; cah1 = nah1; cal1 = nal1;
  }
  int n16 = lane & 15;
  #pragma unroll
  for (int mg=0; mg<2; ++mg){
    #pragma unroll
    for (int r=0; r<4; ++r){
      int P = Pbase + mg*16 + q*4 + r;
      if (P < 4752){
        int nn = P/396, pim = P%396;
        #pragma unroll
        for (int nb=0; nb<4; ++nb){
          int co = cog*64 + nb*16 + n16;
          out[((size_t)nn*256+co)*396 + pim] = siluf(acc[mg][nb][r]*bns[co] + bnb[co]);
        }
      }
    }
  }
}

// ---------- heads: depth (40, NCHW) and ctx (64, NHWC) ----------
__global__ __launch_bounds__(256) void k_heads(
    const float* __restrict__ x, const float* __restrict__ dhw, const float* __restrict__ dhb,
    const float* __restrict__ chw, const float* __restrict__ chb,
    float* __restrict__ dep, float* __restrict__ ctx2)
{
  int p = blockIdx.x*256 + threadIdx.x;
  int co = blockIdx.y; int n = blockIdx.z;
  if (p >= 396) return;
  const float* xb = x + (size_t)n*256*396 + p;
  const float* w = (co < 40) ? (dhw + (size_t)co*256) : (chw + (size_t)(co-40)*256);
  float acc = 0.f;
  for (int ci=0; ci<256; ++ci) acc += xb[(size_t)ci*396] * w[ci];
  if (co < 40) dep[((size_t)n*40+co)*396 + p] = acc + dhb[co];
  else { int c = co-40; ctx2[((size_t)n*396+p)*64 + c] = acc + chb[c]; }
}

// ---------- softmax over 40 depth channels ----------
__global__ __launch_bounds__(256) void k_softmax40(float* __restrict__ dep)
{
  int i = blockIdx.x*256 + threadIdx.x;
  if (i >= 12*396) return;
  int n = i/396, p = i%396;
  float* base = dep + (size_t)n*40*396 + p;
  float mx = -1e30f;
  for (int d=0; d<40; ++d) mx = fmaxf(mx, base[(size_t)d*396]);
  float s = 0.f;
  for (int d=0; d<40; ++d){ float e = expf(base[(size_t)d*396]-mx); base[(size_t)d*396]=e; s+=e; }
  float inv = 1.f/s;
  for (int d=0; d<40; ++d) base[(size_t)d*396] *= inv;
}

// ---------- geometry + count (fused) ----------
__global__ __launch_bounds__(256) void k_geom(
    const float* __restrict__ rots, const float* __restrict__ trans,
    const float* __restrict__ intr, int* __restrict__ vox, int* __restrict__ cnt)
{
  int pt = blockIdx.x*256 + threadIdx.x;
  if (pt >= 190080) return;
  int b = pt/95040; int r = pt%95040;
  int n = r/15840;  int r2 = r%15840;
  int d = r2/396;   int pim = r2%396;
  int y = pim/33, x = pim%33;
  int bn = b*6+n;
  const float* R = rots + (size_t)bn*9;
  const float* T = trans + (size_t)bn*3;
  const float* K = intr + (size_t)bn*9;
  float fx=K[0], cx=K[2], fy=K[4], cy=K[5];
  float xs = (float)x * 32.96875f;
  float ys = (float)((double)y * (383.0/11.0));
  float dv = 4.0f + (float)d;
  float camx = (xs-cx)*dv/fx;
  float camy = (ys-cy)*dv/fy;
  float gx = R[0]*camx + R[1]*camy + R[2]*dv + T[0];
  float gy = R[3]*camx + R[4]*camy + R[5]*dv + T[1];
  float gz = R[6]*camx + R[7]*camy + R[8]*dv + T[2];
  int ix = (int)floorf(gx + 50.f);
  int iy = (int)floorf(gy + 50.f);
  int iz = (int)floorf((gz + 10.f)/5.f);
  bool valid = (ix>=0 && ix<100 && iy>=0 && iy<100 && iz>=0 && iz<4);
  int sid = iz*10000 + ix*100 + iy;
  vox[pt] = valid ? sid : -1;
  if (valid) atomicAdd(&cnt[b*40000 + sid], 1);
}

// ---------- scan ----------
__global__ __launch_bounds__(256) void k_scan1(
    const int* __restrict__ cnt, int* __restrict__ off, int* __restrict__ bsum)
{
  __shared__ int s[256];
  int t = threadIdx.x;
  int i = blockIdx.x*256 + t;
  int v = (i < 80000) ? cnt[i] : 0;
  s[t] = v; __syncthreads();
  for (int o=1;o<256;o<<=1){
    int x = (t>=o) ? s[t-o] : 0;
    __syncthreads();
    s[t] += x;
    __syncthreads();
  }
  if (i < 80000) off[i] = s[t] - v;
  if (t == 255) bsum[blockIdx.x] = s[255];
}

__global__ void k_scan2(int* __restrict__ bsum, int nblk)
{
  if (threadIdx.x==0 && blockIdx.x==0){
    int run = 0;
    for (int j=0;j<nblk;++j){ int t = bsum[j]; bsum[j] = run; run += t; }
  }
}

__global__ __launch_bounds__(256) void k_scan3(
    int* __restrict__ off, const int* __restrict__ bsum, int* __restrict__ cur)
{
  int i = blockIdx.x*256 + threadIdx.x;
  if (i >= 80000) return;
  int o = off[i] + bsum[i>>8];
  off[i] = o;
  cur[i] = o;
}

__global__ __launch_bounds__(256) void k_fill(
    const int* __restrict__ vox, int* __restrict__ cur, int* __restrict__ list)
{
  int pt = blockIdx.x*256 + threadIdx.x;
  if (pt >= 190080) return;
  int s = vox[pt];
  if (s < 0) return;
  int b = pt/95040;
  int slot = atomicAdd(&cur[b*40000 + s], 1);
  list[slot] = pt;
}

// ---------- gather: one wave per (b,sid), lane=channel ----------
__global__ __launch_bounds__(256) void k_gather(
    const int* __restrict__ off, const int* __restrict__ cnt, const int* __restrict__ list,
    const float* __restrict__ ctx2, const float* __restrict__ dep, float* __restrict__ bev)
{
  int tid = threadIdx.x;
  int bv = blockIdx.x*4 + (tid>>6);
  int c = tid & 63;
  int b = bv/40000, sid = bv%40000;
  int st = off[bv], nn = cnt[bv];
  float s = 0.f;
  for (int k=0;k<nn;++k){
    int pt = list[st+k];
    int r = pt%95040;
    int bn = b*6 + r/15840;
    int r2 = r%15840;
    int dd = r2/396, pim = r2%396;
    s += ctx2[((size_t)bn*396+pim)*64 + c] * dep[((size_t)bn*40+dd)*396 + pim];
  }
  int iz = sid/10000, rem = sid%10000;
  bev[(size_t)b*2560000 + (size_t)iz*640000 + (size_t)c*10000 + rem] = s;
}

// ---------- NCHW fp32 (*g) -> padded NHWC bf16 hi/lo, coalesced LDS transpose ----------
// grid (102, 2, 8): padded row py, batch b, ci-group of 32
__global__ __launch_bounds__(256) void k_tohwc2(
    const float* __restrict__ in, hb* __restrict__ Ah, hb* __restrict__ Al,
    const float* __restrict__ g)
{
  __shared__ float tile[32*105];
  int py = blockIdx.x;
  int b  = blockIdx.y;
  int cg = blockIdx.z;
  int tid = threadIdx.x;
  bool inner = (py >= 1 && py <= 100);
  if (inner){
    if (tid < 64){ int cil = tid & 31; int col = (tid>>5) ? 101 : 0; tile[cil*105 + col] = 0.f; }
    for (int i = tid; i < 3200; i += 256){
      int cil = i / 100, x = i % 100;
      int ci = cg*32 + cil;
      tile[cil*105 + (x+1)] = in[(((size_t)b*256 + ci)*100 + (py-1))*100 + x];
    }
  }
  __syncthreads();
  for (int i = tid; i < 32*102; i += 256){
    int px = i >> 5, cil = i & 31;
    int ci = cg*32 + cil;
    float v = 0.f;
    if (inner){
      v = tile[cil*105 + px];
      if (g) v *= g[b*256 + ci];
    }
    hb hv, lv; split2(v, &hv, &lv);
    size_t o = (((size_t)b*102 + py)*102 + px)*256 + ci;
    Ah[o] = hv; Al[o] = lv;
  }
}

// ---------- row mean (NCHW rows) ----------
__global__ __launch_bounds__(256) void k_rowmean(
    const float* __restrict__ in, float* __restrict__ out, int rowlen, float inv)
{
  __shared__ float ws[4];
  int row = blockIdx.x; int t = threadIdx.x;
  const float* p = in + (size_t)row*rowlen;
  float s = 0.f;
  for (int i=t; i<rowlen; i+=256) s += p[i];
  #pragma unroll
  for (int off=32; off; off>>=1) s += __shfl_down(s, off);
  if ((t&63)==0) ws[t>>6] = s;
  __syncthreads();
  if (t==0) out[row] = (ws[0]+ws[1]+ws[2]+ws[3]) * inv;
}

// ---------- BEV MFMA conv with LDS A-staging ----------
// flat grid L: spatial = L/(NBG*2) -> (xg=spatial%7, yg=spatial/7);
// rem = L%(NBG*2): cog = rem%NBG, bb = rem/NBG  (XCD gets fixed (cog,bb), spatial sweep)
// K-loop: kb outer (A chunk staged in LDS), tap inner (B streamed, kb-major pack).
__global__ __launch_bounds__(256) void k_conv3_bevm(
    const hb* __restrict__ Ah, const hb* __restrict__ Al,
    const hb* __restrict__ Wph, const hb* __restrict__ Wpl,
    const float* __restrict__ bns, const float* __restrict__ bnb,
    const float* __restrict__ res, float* __restrict__ out, int Cout, int NBG)
{
  __shared__ __align__(16) short sAh[10*18*40];   // 14.4 KB
  __shared__ __align__(16) short sAl[10*18*40];
  __shared__ short8 lbh[256], lbl[256];           // 8 KB
  const int NB = Cout >> 4;
  int tid = threadIdx.x;
  int wv = tid >> 6, lane = tid & 63;
  int L = blockIdx.x;
  int spatial = L / (NBG*2);
  int rem = L % (NBG*2);
  int cog = rem % NBG;
  int bb  = rem / NBG;
  int xg = spatial % 7, yg = spatial / 7;
  int x0 = xg*16;
  int y0 = yg*8 + wv;
  int m = lane & 15, q = lane >> 4;
  int nb0 = cog*4;
  floatx4 acc[2][4];
  #pragma unroll
  for (int i=0;i<2;++i)
    #pragma unroll
    for (int j=0;j<4;++j) acc[i][j] = (floatx4)(0.f);

  const short8* gAh = (const short8*)(const void*)Ah;
  const short8* gAl = (const short8*)(const void*)Al;
  const short8* gWh = (const short8*)(const void*)Wph;
  const short8* gWl = (const short8*)(const void*)Wpl;
  const size_t nbstride = (size_t)NB*64;
  const size_t sb = (size_t)(nb0 + wv)*64 + lane;

  short8 ph = gWh[sb], pl = gWl[sb];

  for (int kb=0; kb<8; ++kb){
    #pragma unroll 3
    for (int tap=0; tap<9; ++tap){
      int idx2 = kb*9 + tap;
      __syncthreads();                 // prior LDS reads (A and B) done
      lbh[tid] = ph; lbl[tid] = pl;
      if (tap == 0){
        // stage A chunk for ci range [kb*32, kb*32+32)
        for (int i = tid; i < 720; i += 256){
          int rc = i >> 2, part = i & 3;
          int r = rc / 18, c = rc % 18;
          int yr = yg*8 + r; if (yr > 101) yr = 101;
          int xc = x0 + c;   if (xc > 101) xc = 101;
          size_t so = ((size_t)((bb*102 + yr)*102 + xc))*32 + kb*4 + part;
          short8 vh = gAh[so], vl = gAl[so];
          int dst = (r*18 + c)*40 + part*8;
          *(short8*)(sAh + dst) = vh;
          *(short8*)(sAl + dst) = vl;
        }
      }
      int nx = (idx2+1 < 72) ? idx2+1 : 71;
      ph = gWh[(size_t)nx*nbstride + sb];
      pl = gWl[(size_t)nx*nbstride + sb];
      __syncthreads();                 // staged A+B visible
      int dy = (tap*11) >> 5;          // tap/3
      int dx = tap - dy*3;
      int cc = dx + m;
      int a0 = ((wv + dy)*18 + cc)*40 + q*8;
      int a1 = ((wv + 4 + dy)*18 + cc)*40 + q*8;
      short8 cah0 = *(const short8*)(sAh + a0);
      short8 cal0 = *(const short8*)(sAl + a0);
      short8 cah1 = *(const short8*)(sAh + a1);
      short8 cal1 = *(const short8*)(sAl + a1);
      #pragma unroll
      for (int nb=0; nb<4; ++nb){
        short8 bh = lbh[nb*64 + lane];
        short8 bl = lbl[nb*64 + lane];
        acc[0][nb] = __builtin_amdgcn_mfma_f32_16x16x32_bf16(cah0, bh, acc[0][nb], 0,0,0);
        acc[0][nb] = __builtin_amdgcn_mfma_f32_16x16x32_bf16(cah0, bl, acc[0][nb], 0,0,0);
        acc[0][nb] = __builtin_amdgcn_mfma_f32_16x16x32_bf16(cal0, bh, acc[0][nb], 0,0,0);
        acc[1][nb] = __builtin_amdgcn_mfma_f32_16x16x32_bf16(cah1, bh, acc[1][nb], 0,0,0);
        acc[1][nb] = __builtin_amdgcn_mfma_f32_16x16x32_bf16(cah1, bl, acc[1][nb], 0,0,0);
        acc[1][nb] = __builtin_amdgcn_mfma_f32_16x16x32_bf16(cal1, bh, acc[1][nb], 0,0,0);
      }
    }
  }

  int n = lane & 15;
  int xq = x0 + q*4;
  #pragma unroll
  for (int mg=0; mg<2; ++mg){
    int yo = y0 + mg*4;
    if (yo < 100 && xq < 100){
      #pragma unroll
      for (int nb=0; nb<4; ++nb){
        int co = cog*64 + nb*16 + n;
        float s = bns[co], bv = bnb[co];
        floatx4 a = acc[mg][nb];
        float4 v;
        v.x = fmaxf(a[0]*s+bv, 0.f);
        v.y = fmaxf(a[1]*s+bv, 0.f);
        v.z = fmaxf(a[2]*s+bv, 0.f);
        v.w = fmaxf(a[3]*s+bv, 0.f);
        size_t o = ((size_t)(bb*Cout+co)*100 + yo)*100 + xq;
        if (res){
          float4 rv = *(const float4*)(res + o);
          v.x += rv.x; v.y += rv.y; v.z += rv.z; v.w += rv.w;
        }
        *(float4*)(out + o) = v;
      }
    }
  }
}

// ---------- final 1x1 conv 128->16 ----------
__global__ __launch_bounds__(256) void k_final(
    const float* __restrict__ h, const float* __restrict__ W, const float* __restrict__ bias,
    float* __restrict__ out)
{
  int pix = blockIdx.x*256 + threadIdx.x;
  int oc = blockIdx.y, b = blockIdx.z;
  if (pix >= 10000) return;
  const float* hb_ = h + (size_t)b*128*10000 + pix;
  const float* w = W + (size_t)oc*128;
  float acc = bias[oc];
  for (int ci=0; ci<128; ++ci) acc += hb_[(size_t)ci*10000]*w[ci];
  out[((size_t)(b*16+oc))*10000 + pix] = acc;
}

extern "C" void kernel_launch(void* const* d_in, const int* in_sizes, int n_in,
                              void* d_out, int out_size, void* d_ws, size_t ws_size,
                              hipStream_t stream)
{
  (void)in_sizes; (void)n_in; (void)out_size; (void)ws_size;
  const float* feats = (const float*)d_in[0];
  const float* rots  = (const float*)d_in[1];
  const float* trans = (const float*)d_in[2];
  const float* intr  = (const float*)d_in[3];
  const float* nw1   = (const float*)d_in[4];
  const float* bn1s  = (const float*)d_in[5];
  const float* bn1b  = (const float*)d_in[6];
  const float* se1w1 = (const float*)d_in[7];
  const float* se1b1 = (const float*)d_in[8];
  const float* se1w2 = (const float*)d_in[9];
  const float* se1b2 = (const float*)d_in[10];
  const float* nw2   = (const float*)d_in[11];
  const float* bn2s  = (const float*)d_in[12];
  const float* bn2b  = (const float*)d_in[13];
  const float* dhw   = (const float*)d_in[14];
  const float* dhb   = (const float*)d_in[15];
  const float* chw   = (const float*)d_in[16];
  const float* chb   = (const float*)d_in[17];
  const float* bcw1  = (const float*)d_in[18];
  const float* bcs1  = (const float*)d_in[19];
  const float* bcb1  = (const float*)d_in[20];
  const float* bcsw1 = (const float*)d_in[21];
  const float* bcsb1 = (const float*)d_in[22];
  const float* bcsw2 = (const float*)d_in[23];
  const float* bcsb2 = (const float*)d_in[24];
  const float* bcw2  = (const float*)d_in[25];
  const float* bcs2  = (const float*)d_in[26];
  const float* bcb2  = (const float*)d_in[27];
  const float* dw1   = (const float*)d_in[28];
  const float* ds1   = (const float*)d_in[29];
  const float* db1   = (const float*)d_in[30];
  const float* dw2   = (const float*)d_in[31];
  const float* db2   = (const float*)d_in[32];
  float* out = (float*)d_out;

  // ---- workspace layout (float units) ----
  float* ws = (float*)d_ws;
  float* bev   = ws;                       // S0: 5,120,000
  float* h1    = ws + 5120000;             // S1: 5,120,000
  hb*    Ah    = (hb*)(ws + 10240000);     // S2: 2,663,424 fu
  hb*    Al    = (hb*)(ws + 12903424);     // S3: 2,663,424 fu
  float* x2    = ws + 15566848;            // S4: 1,216,512
  float* S5    = ws + 16783360;            // 589,824
  float* dep   = ws + 17373184;            // 190,080
  float* ctx2  = ws + 17563264;            // 304,128
  float* mean1 = ws + 17867392;            // 3072
  float* g1    = mean1 + 3072;
  float* mean2 = g1 + 3072;
  float* g2    = mean2 + 512;
  int*   vox   = (int*)(ws + 17875584);    // 190,080 ints
  // phase aliases
  hb* Fh   = (hb*)bev;                     // 3,041,280 fu
  hb* Wc1h = (hb*)(bev + 3041280);         // 163,840 fu (327,680 bf16)
  hb* Wc1l = (hb*)(bev + 3205120);         // 163,840 fu
  float* x1 = h1;                          // NHWC conv1 out (1,216,512 fu)
  hb* Fl   = (hb*)(h1 + 1216512);          // 3,041,280 fu
  hb* Xh   = (hb*)Ah;                      // padded image tile
  hb* Xl   = (hb*)Al;
  hb* Wc2h = (hb*)S5;                      // 294,912 fu
  hb* Wc2l = (hb*)(S5 + 294912);           // 294,912 fu
  int* cnt  = (int*)h1;                    // splat arrays (x1/Fl dead by then)
  int* off  = cnt + 80000;
  int* cur  = off + 80000;
  int* bsum = cur + 80000;
  int* list = bsum + 1024;
  float* h3 = h1;
  hb* Wp1h = (hb*)x2;                      // BEV conv weights (x2 dead after heads)
  hb* Wp1l = (hb*)(x2 + 294912);
  hb* Wp3h = (hb*)(x2 + 589824);
  hb* Wp3l = (hb*)(x2 + 589824 + 147456);
  hb* Wp2h = (hb*)S5;                      // Wc2 dead after conv3s
  hb* Wp2l = (hb*)(S5 + 294912);

  // ---- image branch (MFMA) ----
  k_trans_feats<<<dim3(7,12),256,0,stream>>>(feats,Fh,Fl);
  k_wpack1<<<1280,256,0,stream>>>(nw1,Wc1h,Wc1l);
  k_mfma_gemm1<<<dim3(38,4),256,0,stream>>>(Fh,Fl,Wc1h,Wc1l,bn1s,bn1b,x1);
  k_meanN<<<12,256,0,stream>>>(x1,mean1);
  k_se_fc<<<12,256,0,stream>>>(mean1,se1w1,se1b1,se1w2,se1b2,g1,32);
  k_topad<<<dim3(14,12),256,0,stream>>>(x1,g1,Xh,Xl);
  k_wpack<<<(589824+255)/256,256,0,stream>>>(nw2,Wc2h,Wc2l,16);
  k_conv3s_mfma<<<dim3(38,4),256,0,stream>>>(Xh,Xl,Wc2h,Wc2l,bn2s,bn2b,x2);
  k_heads<<<dim3(2,104,12),256,0,stream>>>(x2,dhw,dhb,chw,chb,dep,ctx2);
  k_softmax40<<<(4752+255)/256,256,0,stream>>>(dep);

  // ---- pack BEV conv weights kb-major (x2, Wc2 dead now) ----
  k_wpackT<<<(589824+255)/256,256,0,stream>>>(bcw1,Wp1h,Wp1l,16);
  k_wpackT<<<(589824+255)/256,256,0,stream>>>(bcw2,Wp2h,Wp2l,16);
  k_wpackT<<<(294912+255)/256,256,0,stream>>>(dw1,Wp3h,Wp3l,8);

  // ---- lift-splat (gather form) ----
  hipMemsetAsync(cnt, 0, 80000*sizeof(int), stream);
  k_geom<<<(190080+255)/256,256,0,stream>>>(rots,trans,intr,vox,cnt);
  k_scan1<<<313,256,0,stream>>>(cnt,off,bsum);
  k_scan2<<<1,64,0,stream>>>(bsum,313);
  k_scan3<<<(80000+255)/256,256,0,stream>>>(off,bsum,cur);
  k_fill<<<(190080+255)/256,256,0,stream>>>(vox,cur,list);
  k_gather<<<20000,256,0,stream>>>(off,cnt,list,ctx2,dep,bev);

  // ---- BEV encoder (MFMA convs, LDS-staged) ----
  k_tohwc2<<<dim3(102,2,8),256,0,stream>>>(bev,Ah,Al,nullptr);
  k_conv3_bevm<<<728,256,0,stream>>>(Ah,Al,Wp1h,Wp1l,bcs1,bcb1,nullptr,h1,256,4);
  k_rowmean<<<512,256,0,stream>>>(h1,mean2,10000,1e-4f);
  k_se_fc<<<2,256,0,stream>>>(mean2,bcsw1,bcsb1,bcsw2,bcsb2,g2,16);
  k_tohwc2<<<dim3(102,2,8),256,0,stream>>>(h1,Ah,Al,g2);   // SE scale fused
  k_conv3_bevm<<<728,256,0,stream>>>(Ah,Al,Wp2h,Wp2l,bcs2,bcb2,bev,bev,256,4);
  k_tohwc2<<<dim3(102,2,8),256,0,stream>>>(bev,Ah,Al,nullptr);
  k_conv3_bevm<<<364,256,0,stream>>>(Ah,Al,Wp3h,Wp3l,ds1,db1,nullptr,h3,128,2);
  k_final<<<dim3(40,16,2),256,0,stream>>>(h3,dw2,db2,out);
}

// Round 8
// 713.169 us; speedup vs baseline: 13.1436x; 1.1000x over previous
//
#include <hip/hip_runtime.h>
#include <hip/hip_bf16.h>
#include <cmath>

// LSS pipeline R8: R7 + k_trans_feats parallelized over ci-chunks
// (84 -> 1680 blocks; was 100us at 3% occupancy, pure latency bound).

typedef __attribute__((ext_vector_type(8))) short short8;
typedef __attribute__((ext_vector_type(4))) float floatx4;
typedef __hip_bfloat16 hb;

__device__ __forceinline__ float sigf(float x){ return 1.0f/(1.0f+expf(-x)); }
__device__ __forceinline__ float siluf(float x){ return x*sigf(x); }
__device__ __forceinline__ void split2(float v, hb* h, hb* l){
  hb hv = __float2bfloat16(v);
  *h = hv; *l = __float2bfloat16(v - __bfloat162float(hv));
}

// ---------- feats NCHW -> NHWC bf16 hi/lo [n][396][1280], one 64x64 tile/block ----------
__global__ __launch_bounds__(256) void k_trans_feats(
    const float* __restrict__ feats, hb* __restrict__ Fh, hb* __restrict__ Fl)
{
  __shared__ float tile[64][65];
  int n = blockIdx.z;
  int p0 = blockIdx.x*64;
  int c0 = blockIdx.y*64;
  int tid = threadIdx.x;
  int tr = tid >> 6;      // 0..3
  int tc = tid & 63;
  #pragma unroll
  for (int it=0; it<16; ++it){
    int ci = c0 + it*4 + tr;
    int p = p0 + tc;
    float v = 0.f;
    if (p < 396) v = feats[((size_t)n*1280 + ci)*396 + p];
    tile[it*4+tr][tc] = v;
  }
  __syncthreads();
  #pragma unroll
  for (int it=0; it<16; ++it){
    int pl = it*4 + tr;
    int p = p0 + pl;
    if (p < 396){
      hb hv, lv; split2(tile[tc][pl], &hv, &lv);
      size_t o = ((size_t)n*396 + p)*1280 + c0 + tc;
      Fh[o] = hv; Fl[o] = lv;
    }
  }
}

// ---------- pack 1x1 weights [256][1280] -> [(kb*16+nb)*64+lane][8] ----------
__global__ __launch_bounds__(256) void k_wpack1(
    const float* __restrict__ W, hb* __restrict__ Wph, hb* __restrict__ Wpl)
{
  int i = blockIdx.x*256 + threadIdx.x;
  if (i >= 40*16*512) return;
  int j = i & 7;
  int lane = (i>>3) & 63;
  int t2 = i >> 9;
  int nb = t2 & 15;
  int kb = t2 >> 4;
  int ci = kb*32 + (lane>>4)*8 + j;
  int co = nb*16 + (lane&15);
  hb hv, lv; split2(W[(size_t)co*1280 + ci], &hv, &lv);
  Wph[i] = hv; Wpl[i] = lv;
}

// ---------- pack 3x3 weights tap-major (image conv) ----------
__global__ __launch_bounds__(256) void k_wpack(
    const float* __restrict__ W, hb* __restrict__ Wph, hb* __restrict__ Wpl, int NB)
{
  int i = blockIdx.x*256 + threadIdx.x;
  int total = 9*8*NB*512;
  if (i >= total) return;
  int j = i & 7;
  int t1 = i >> 3;
  int lane = t1 & 63;
  int t2 = t1 >> 6;
  int nb = t2 % NB;
  int t3 = t2 / NB;
  int kb = t3 & 7;
  int tap = t3 >> 3;
  int ci = kb*32 + (lane>>4)*8 + j;
  int co = nb*16 + (lane&15);
  hb hv, lv; split2(W[(size_t)co*2304 + ci*9 + tap], &hv, &lv);
  Wph[i] = hv; Wpl[i] = lv;
}

// ---------- pack 3x3 weights kb-major (BEV conv) ----------
__global__ __launch_bounds__(256) void k_wpackT(
    const float* __restrict__ W, hb* __restrict__ Wph, hb* __restrict__ Wpl, int NB)
{
  int i = blockIdx.x*256 + threadIdx.x;
  int total = 9*8*NB*512;
  if (i >= total) return;
  int j = i & 7;
  int t1 = i >> 3;
  int lane = t1 & 63;
  int t2 = t1 >> 6;
  int nb = t2 % NB;
  int t3 = t2 / NB;
  int tap = t3 % 9;
  int kb = t3 / 9;
  int ci = kb*32 + (lane>>4)*8 + j;
  int co = nb*16 + (lane&15);
  hb hv, lv; split2(W[(size_t)co*2304 + ci*9 + tap], &hv, &lv);
  Wph[i] = hv; Wpl[i] = lv;
}

// ---------- conv1 as MFMA GEMM: M=4752, N=256, K=1280; BN+SiLU; out NHWC ----------
__global__ __launch_bounds__(256) void k_mfma_gemm1(
    const hb* __restrict__ Fh, const hb* __restrict__ Fl,
    const hb* __restrict__ Wph, const hb* __restrict__ Wpl,
    const float* __restrict__ bns, const float* __restrict__ bnb,
    float* __restrict__ out)
{
  __shared__ short8 lbh[256], lbl[256];
  int tid = threadIdx.x;
  int wv = tid >> 6, lane = tid & 63;
  int cog = blockIdx.y;
  int Pbase = blockIdx.x*128 + wv*32;
  int m = lane & 15, q = lane >> 4;
  int P0 = Pbase + m;      if (P0 > 4751) P0 = 4751;
  int P1 = Pbase + 16 + m; if (P1 > 4751) P1 = 4751;
  size_t rA0 = (size_t)P0*160 + q;
  size_t rA1 = (size_t)P1*160 + q;
  const short8* gAh = (const short8*)(const void*)Fh;
  const short8* gAl = (const short8*)(const void*)Fl;
  const short8* gWh = (const short8*)(const void*)Wph;
  const short8* gWl = (const short8*)(const void*)Wpl;
  size_t sb = (size_t)(cog*4 + wv)*64 + lane;
  floatx4 acc[2][4];
  #pragma unroll
  for (int i=0;i<2;++i)
    #pragma unroll
    for (int j=0;j<4;++j) acc[i][j] = (floatx4)(0.f);
  short8 ph = gWh[sb], pw = gWl[sb];
  short8 cah0 = gAh[rA0], cal0 = gAl[rA0], cah1 = gAh[rA1], cal1 = gAl[rA1];
  for (int kb=0; kb<40; ++kb){
    __syncthreads();
    lbh[tid] = ph; lbl[tid] = pw;
    int nx = (kb+1 < 40) ? kb+1 : 39;
    ph = gWh[(size_t)nx*1024 + sb]; pw = gWl[(size_t)nx*1024 + sb];
    __syncthreads();
    short8 nah0 = gAh[rA0 + (size_t)nx*4];
    short8 nal0 = gAl[rA0 + (size_t)nx*4];
    short8 nah1 = gAh[rA1 + (size_t)nx*4];
    short8 nal1 = gAl[rA1 + (size_t)nx*4];
    #pragma unroll
    for (int nb=0; nb<4; ++nb){
      short8 bh = lbh[nb*64 + lane];
      short8 bl = lbl[nb*64 + lane];
      acc[0][nb] = __builtin_amdgcn_mfma_f32_16x16x32_bf16(cah0, bh, acc[0][nb], 0,0,0);
      acc[0][nb] = __builtin_amdgcn_mfma_f32_16x16x32_bf16(cah0, bl, acc[0][nb], 0,0,0);
      acc[0][nb] = __builtin_amdgcn_mfma_f32_16x16x32_bf16(cal0, bh, acc[0][nb], 0,0,0);
      acc[1][nb] = __builtin_amdgcn_mfma_f32_16x16x32_bf16(cah1, bh, acc[1][nb], 0,0,0);
      acc[1][nb] = __builtin_amdgcn_mfma_f32_16x16x32_bf16(cah1, bl, acc[1][nb], 0,0,0);
      acc[1][nb] = __builtin_amdgcn_mfma_f32_16x16x32_bf16(cal1, bh, acc[1][nb], 0,0,0);
    }
    cah0 = nah0; cal0 = nal0; cah1 = nah1; cal1 = nal1;
  }
  int n16 = lane & 15;
  #pragma unroll
  for (int mg=0; mg<2; ++mg){
    #pragma unroll
    for (int nb=0; nb<4; ++nb){
      int co = cog*64 + nb*16 + n16;
      float s = bns[co], bv = bnb[co];
      #pragma unroll
      for (int r=0; r<4; ++r){
        int P = Pbase + mg*16 + q*4 + r;
        if (P < 4752) out[(size_t)P*256 + co] = siluf(acc[mg][nb][r]*s + bv);
      }
    }
  }
}

// ---------- NHWC mean over 396 pixels ----------
__global__ __launch_bounds__(256) void k_meanN(
    const float* __restrict__ x1, float* __restrict__ mean)
{
  int n = blockIdx.x; int c = threadIdx.x;
  float s = 0.f;
  for (int p=0; p<396; ++p) s += x1[((size_t)n*396+p)*256 + c];
  mean[n*256+c] = s*(1.f/396.f);
}

// ---------- SE FC ----------
__global__ __launch_bounds__(256) void k_se_fc(
    const float* __restrict__ mean, const float* __restrict__ w1, const float* __restrict__ b1,
    const float* __restrict__ w2, const float* __restrict__ b2, float* __restrict__ g, int H)
{
  __shared__ float m[256];
  __shared__ float h[32];
  int n = blockIdx.x; int t = threadIdx.x;
  m[t] = mean[n*256 + t];
  __syncthreads();
  if (t < H){
    float s = b1[t];
    for (int c=0; c<256; ++c) s += m[c]*w1[t*256+c];
    h[t] = siluf(s);
  }
  __syncthreads();
  float s = b2[t];
  for (int j=0; j<H; ++j) s += h[j]*w2[t*H+j];
  g[n*256+t] = sigf(s);
}

// ---------- x1 NHWC * g -> padded [n][14][35][256] bf16 hi/lo ----------
__global__ __launch_bounds__(256) void k_topad(
    const float* __restrict__ x1, const float* __restrict__ g,
    hb* __restrict__ Xh, hb* __restrict__ Xl)
{
  int y = blockIdx.x;   // 0..13
  int n = blockIdx.y;
  int c = threadIdx.x;
  float gc = g[n*256+c];
  for (int xx=0; xx<35; ++xx){
    float v = 0.f;
    if (y>=1 && y<=12 && xx>=1 && xx<=33)
      v = x1[((size_t)n*396 + (y-1)*33 + (xx-1))*256 + c]*gc;
    hb hv, lv; split2(v, &hv, &lv);
    size_t o = (((size_t)n*14+y)*35+xx)*256 + c;
    Xh[o] = hv; Xl[o] = lv;
  }
}

// ---------- image 3x3 conv as implicit MFMA GEMM: M=4752, N=256, K=2304; out NCHW ----------
__global__ __launch_bounds__(256) void k_conv3s_mfma(
    const hb* __restrict__ Xh, const hb* __restrict__ Xl,
    const hb* __restrict__ Wph, const hb* __restrict__ Wpl,
    const float* __restrict__ bns, const float* __restrict__ bnb,
    float* __restrict__ out)
{
  __shared__ short8 lbh[256], lbl[256];
  int tid = threadIdx.x;
  int wv = tid >> 6, lane = tid & 63;
  int cog = blockIdx.y;
  int Pbase = blockIdx.x*128 + wv*32;
  int m = lane & 15, q = lane >> 4;
  int P0 = Pbase + m;      if (P0 > 4751) P0 = 4751;
  int P1 = Pbase + 16 + m; if (P1 > 4751) P1 = 4751;
  int n0 = P0/396, pim0 = P0%396;
  int n1 = P1/396, pim1 = P1%396;
  size_t base0 = (size_t)((n0*14 + pim0/33)*35 + pim0%33)*32 + q;
  size_t base1 = (size_t)((n1*14 + pim1/33)*35 + pim1%33)*32 + q;
  const short8* gAh = (const short8*)(const void*)Xh;
  const short8* gAl = (const short8*)(const void*)Xl;
  const short8* gWh = (const short8*)(const void*)Wph;
  const short8* gWl = (const short8*)(const void*)Wpl;
  size_t sb = (size_t)(cog*4 + wv)*64 + lane;
  floatx4 acc[2][4];
  #pragma unroll
  for (int i=0;i<2;++i)
    #pragma unroll
    for (int j=0;j<4;++j) acc[i][j] = (floatx4)(0.f);
  short8 ph = gWh[sb], pw = gWl[sb];
  short8 cah0 = gAh[base0], cal0 = gAl[base0], cah1 = gAh[base1], cal1 = gAl[base1];
  for (int idx=0; idx<72; ++idx){
    __syncthreads();
    lbh[tid] = ph; lbl[tid] = pw;
    int nx = (idx+1 < 72) ? idx+1 : 71;
    ph = gWh[(size_t)nx*1024 + sb]; pw = gWl[(size_t)nx*1024 + sb];
    __syncthreads();
    int tap = nx >> 3, kb = nx & 7;
    int dy = (tap*11) >> 5;            // tap/3
    int dx = tap - dy*3;
    int ao = (dy*35+dx)*32 + kb*4;
    short8 nah0 = gAh[base0 + ao];
    short8 nal0 = gAl[base0 + ao];
    short8 nah1 = gAh[base1 + ao];
    short8 nal1 = gAl[base1 + ao];
    #pragma unroll
    for (int nb=0; nb<4; ++nb){
      short8 bh = lbh[nb*64 + lane];
      short8 bl = lbl[nb*64 + lane];
      acc[0][nb] = __builtin_amdgcn_mfma_f32_16x16x32_bf16(cah0, bh, acc[0][nb], 0,0,0);
      acc[0][nb] = __builtin_amdgcn_mfma_f32_16x16x32_bf16(cah0, bl, acc[0][nb], 0,0,0);
      acc[0][nb] = __builtin_amdgcn_mfma_f32_16x16x32_bf16(cal0, bh, acc[0][nb], 0,0,0);
      acc[1][nb] = __builtin_amdgcn_mfma_f32_16x16x32_bf16(cah1, bh, acc[1][nb], 0,0,0);
      acc[1][nb] = __builtin_amdgcn_mfma_f32_16x16x32_bf16(cah1, bl, acc[1][nb], 0,0,0);
      acc[1][nb] = __builtin_amdgcn_mfma_f32_16x16x32_bf16(cal1, bh, acc[1][nb], 0,0,0);
    }
    cah0 = nah0; cal0 = nal0; cah1 = nah1; cal1 = nal1;
  }
  int n16 = lane & 15;
  #pragma unroll
  for (int mg=0; mg<2; ++mg){
    #pragma unroll
    for (int r=0; r<4; ++r){
      int P = Pbase + mg*16 + q*4 + r;
      if (P < 4752){
        int nn = P/396, pim = P%396;
        #pragma unroll
        for (int nb=0; nb<4; ++nb){
          int co = cog*64 + nb*16 + n16;
          out[((size_t)nn*256+co)*396 + pim] = siluf(acc[mg][nb][r]*bns[co] + bnb[co]);
        }
      }
    }
  }
}

// ---------- heads: depth (40, NCHW) and ctx (64, NHWC) ----------
__global__ __launch_bounds__(256) void k_heads(
    const float* __restrict__ x, const float* __restrict__ dhw, const float* __restrict__ dhb,
    const float* __restrict__ chw, const float* __restrict__ chb,
    float* __restrict__ dep, float* __restrict__ ctx2)
{
  int p = blockIdx.x*256 + threadIdx.x;
  int co = blockIdx.y; int n = blockIdx.z;
  if (p >= 396) return;
  const float* xb = x + (size_t)n*256*396 + p;
  const float* w = (co < 40) ? (dhw + (size_t)co*256) : (chw + (size_t)(co-40)*256);
  float acc = 0.f;
  for (int ci=0; ci<256; ++ci) acc += xb[(size_t)ci*396] * w[ci];
  if (co < 40) dep[((size_t)n*40+co)*396 + p] = acc + dhb[co];
  else { int c = co-40; ctx2[((size_t)n*396+p)*64 + c] = acc + chb[c]; }
}

// ---------- softmax over 40 depth channels ----------
__global__ __launch_bounds__(256) void k_softmax40(float* __restrict__ dep)
{
  int i = blockIdx.x*256 + threadIdx.x;
  if (i >= 12*396) return;
  int n = i/396, p = i%396;
  float* base = dep + (size_t)n*40*396 + p;
  float mx = -1e30f;
  for (int d=0; d<40; ++d) mx = fmaxf(mx, base[(size_t)d*396]);
  float s = 0.f;
  for (int d=0; d<40; ++d){ float e = expf(base[(size_t)d*396]-mx); base[(size_t)d*396]=e; s+=e; }
  float inv = 1.f/s;
  for (int d=0; d<40; ++d) base[(size_t)d*396] *= inv;
}

// ---------- geometry + count (fused) ----------
__global__ __launch_bounds__(256) void k_geom(
    const float* __restrict__ rots, const float* __restrict__ trans,
    const float* __restrict__ intr, int* __restrict__ vox, int* __restrict__ cnt)
{
  int pt = blockIdx.x*256 + threadIdx.x;
  if (pt >= 190080) return;
  int b = pt/95040; int r = pt%95040;
  int n = r/15840;  int r2 = r%15840;
  int d = r2/396;   int pim = r2%396;
  int y = pim/33, x = pim%33;
  int bn = b*6+n;
  const float* R = rots + (size_t)bn*9;
  const float* T = trans + (size_t)bn*3;
  const float* K = intr + (size_t)bn*9;
  float fx=K[0], cx=K[2], fy=K[4], cy=K[5];
  float xs = (float)x * 32.96875f;
  float ys = (float)((double)y * (383.0/11.0));
  float dv = 4.0f + (float)d;
  float camx = (xs-cx)*dv/fx;
  float camy = (ys-cy)*dv/fy;
  float gx = R[0]*camx + R[1]*camy + R[2]*dv + T[0];
  float gy = R[3]*camx + R[4]*camy + R[5]*dv + T[1];
  float gz = R[6]*camx + R[7]*camy + R[8]*dv + T[2];
  int ix = (int)floorf(gx + 50.f);
  int iy = (int)floorf(gy + 50.f);
  int iz = (int)floorf((gz + 10.f)/5.f);
  bool valid = (ix>=0 && ix<100 && iy>=0 && iy<100 && iz>=0 && iz<4);
  int sid = iz*10000 + ix*100 + iy;
  vox[pt] = valid ? sid : -1;
  if (valid) atomicAdd(&cnt[b*40000 + sid], 1);
}

// ---------- scan ----------
__global__ __launch_bounds__(256) void k_scan1(
    const int* __restrict__ cnt, int* __restrict__ off, int* __restrict__ bsum)
{
  __shared__ int s[256];
  int t = threadIdx.x;
  int i = blockIdx.x*256 + t;
  int v = (i < 80000) ? cnt[i] : 0;
  s[t] = v; __syncthreads();
  for (int o=1;o<256;o<<=1){
    int x = (t>=o) ? s[t-o] : 0;
    __syncthreads();
    s[t] += x;
    __syncthreads();
  }
  if (i < 80000) off[i] = s[t] - v;
  if (t == 255) bsum[blockIdx.x] = s[255];
}

__global__ void k_scan2(int* __restrict__ bsum, int nblk)
{
  if (threadIdx.x==0 && blockIdx.x==0){
    int run = 0;
    for (int j=0;j<nblk;++j){ int t = bsum[j]; bsum[j] = run; run += t; }
  }
}

__global__ __launch_bounds__(256) void k_scan3(
    int* __restrict__ off, const int* __restrict__ bsum, int* __restrict__ cur)
{
  int i = blockIdx.x*256 + threadIdx.x;
  if (i >= 80000) return;
  int o = off[i] + bsum[i>>8];
  off[i] = o;
  cur[i] = o;
}

__global__ __launch_bounds__(256) void k_fill(
    const int* __restrict__ vox, int* __restrict__ cur, int* __restrict__ list)
{
  int pt = blockIdx.x*256 + threadIdx.x;
  if (pt >= 190080) return;
  int s = vox[pt];
  if (s < 0) return;
  int b = pt/95040;
  int slot = atomicAdd(&cur[b*40000 + s], 1);
  list[slot] = pt;
}

// ---------- gather: one wave per (b,sid), lane=channel ----------
__global__ __launch_bounds__(256) void k_gather(
    const int* __restrict__ off, const int* __restrict__ cnt, const int* __restrict__ list,
    const float* __restrict__ ctx2, const float* __restrict__ dep, float* __restrict__ bev)
{
  int tid = threadIdx.x;
  int bv = blockIdx.x*4 + (tid>>6);
  int c = tid & 63;
  int b = bv/40000, sid = bv%40000;
  int st = off[bv], nn = cnt[bv];
  float s = 0.f;
  for (int k=0;k<nn;++k){
    int pt = list[st+k];
    int r = pt%95040;
    int bn = b*6 + r/15840;
    int r2 = r%15840;
    int dd = r2/396, pim = r2%396;
    s += ctx2[((size_t)bn*396+pim)*64 + c] * dep[((size_t)bn*40+dd)*396 + pim];
  }
  int iz = sid/10000, rem = sid%10000;
  bev[(size_t)b*2560000 + (size_t)iz*640000 + (size_t)c*10000 + rem] = s;
}

// ---------- NCHW fp32 (*g) -> padded NHWC bf16 hi/lo, coalesced LDS transpose ----------
__global__ __launch_bounds__(256) void k_tohwc2(
    const float* __restrict__ in, hb* __restrict__ Ah, hb* __restrict__ Al,
    const float* __restrict__ g)
{
  __shared__ float tile[32*105];
  int py = blockIdx.x;
  int b  = blockIdx.y;
  int cg = blockIdx.z;
  int tid = threadIdx.x;
  bool inner = (py >= 1 && py <= 100);
  if (inner){
    if (tid < 64){ int cil = tid & 31; int col = (tid>>5) ? 101 : 0; tile[cil*105 + col] = 0.f; }
    for (int i = tid; i < 3200; i += 256){
      int cil = i / 100, x = i % 100;
      int ci = cg*32 + cil;
      tile[cil*105 + (x+1)] = in[(((size_t)b*256 + ci)*100 + (py-1))*100 + x];
    }
  }
  __syncthreads();
  for (int i = tid; i < 32*102; i += 256){
    int px = i >> 5, cil = i & 31;
    int ci = cg*32 + cil;
    float v = 0.f;
    if (inner){
      v = tile[cil*105 + px];
      if (g) v *= g[b*256 + ci];
    }
    hb hv, lv; split2(v, &hv, &lv);
    size_t o = (((size_t)b*102 + py)*102 + px)*256 + ci;
    Ah[o] = hv; Al[o] = lv;
  }
}

// ---------- row mean (NCHW rows) ----------
__global__ __launch_bounds__(256) void k_rowmean(
    const float* __restrict__ in, float* __restrict__ out, int rowlen, float inv)
{
  __shared__ float ws[4];
  int row = blockIdx.x; int t = threadIdx.x;
  const float* p = in + (size_t)row*rowlen;
  float s = 0.f;
  for (int i=t; i<rowlen; i+=256) s += p[i];
  #pragma unroll
  for (int off=32; off; off>>=1) s += __shfl_down(s, off);
  if ((t&63)==0) ws[t>>6] = s;
  __syncthreads();
  if (t==0) out[row] = (ws[0]+ws[1]+ws[2]+ws[3]) * inv;
}

// ---------- BEV MFMA conv with LDS A-staging ----------
__global__ __launch_bounds__(256) void k_conv3_bevm(
    const hb* __restrict__ Ah, const hb* __restrict__ Al,
    const hb* __restrict__ Wph, const hb* __restrict__ Wpl,
    const float* __restrict__ bns, const float* __restrict__ bnb,
    const float* __restrict__ res, float* __restrict__ out, int Cout, int NBG)
{
  __shared__ __align__(16) short sAh[10*18*40];
  __shared__ __align__(16) short sAl[10*18*40];
  __shared__ short8 lbh[256], lbl[256];
  const int NB = Cout >> 4;
  int tid = threadIdx.x;
  int wv = tid >> 6, lane = tid & 63;
  int L = blockIdx.x;
  int spatial = L / (NBG*2);
  int rem = L % (NBG*2);
  int cog = rem % NBG;
  int bb  = rem / NBG;
  int xg = spatial % 7, yg = spatial / 7;
  int x0 = xg*16;
  int y0 = yg*8 + wv;
  int m = lane & 15, q = lane >> 4;
  int nb0 = cog*4;
  floatx4 acc[2][4];
  #pragma unroll
  for (int i=0;i<2;++i)
    #pragma unroll
    for (int j=0;j<4;++j) acc[i][j] = (floatx4)(0.f);

  const short8* gAh = (const short8*)(const void*)Ah;
  const short8* gAl = (const short8*)(const void*)Al;
  const short8* gWh = (const short8*)(const void*)Wph;
  const short8* gWl = (const short8*)(const void*)Wpl;
  const size_t nbstride = (size_t)NB*64;
  const size_t sb = (size_t)(nb0 + wv)*64 + lane;

  short8 ph = gWh[sb], pl = gWl[sb];

  for (int kb=0; kb<8; ++kb){
    #pragma unroll 3
    for (int tap=0; tap<9; ++tap){
      int idx2 = kb*9 + tap;
      __syncthreads();
      lbh[tid] = ph; lbl[tid] = pl;
      if (tap == 0){
        for (int i = tid; i < 720; i += 256){
          int rc = i >> 2, part = i & 3;
          int r = rc / 18, c = rc % 18;
          int yr = yg*8 + r; if (yr > 101) yr = 101;
          int xc = x0 + c;   if (xc > 101) xc = 101;
          size_t so = ((size_t)((bb*102 + yr)*102 + xc))*32 + kb*4 + part;
          short8 vh = gAh[so], vl = gAl[so];
          int dst = (r*18 + c)*40 + part*8;
          *(short8*)(sAh + dst) = vh;
          *(short8*)(sAl + dst) = vl;
        }
      }
      int nx = (idx2+1 < 72) ? idx2+1 : 71;
      ph = gWh[(size_t)nx*nbstride + sb];
      pl = gWl[(size_t)nx*nbstride + sb];
      __syncthreads();
      int dy = (tap*11) >> 5;
      int dx = tap - dy*3;
      int cc = dx + m;
      int a0 = ((wv + dy)*18 + cc)*40 + q*8;
      int a1 = ((wv + 4 + dy)*18 + cc)*40 + q*8;
      short8 cah0 = *(const short8*)(sAh + a0);
      short8 cal0 = *(const short8*)(sAl + a0);
      short8 cah1 = *(const short8*)(sAh + a1);
      short8 cal1 = *(const short8*)(sAl + a1);
      #pragma unroll
      for (int nb=0; nb<4; ++nb){
        short8 bh = lbh[nb*64 + lane];
        short8 bl = lbl[nb*64 + lane];
        acc[0][nb] = __builtin_amdgcn_mfma_f32_16x16x32_bf16(cah0, bh, acc[0][nb], 0,0,0);
        acc[0][nb] = __builtin_amdgcn_mfma_f32_16x16x32_bf16(cah0, bl, acc[0][nb], 0,0,0);
        acc[0][nb] = __builtin_amdgcn_mfma_f32_16x16x32_bf16(cal0, bh, acc[0][nb], 0,0,0);
        acc[1][nb] = __builtin_amdgcn_mfma_f32_16x16x32_bf16(cah1, bh, acc[1][nb], 0,0,0);
        acc[1][nb] = __builtin_amdgcn_mfma_f32_16x16x32_bf16(cah1, bl, acc[1][nb], 0,0,0);
        acc[1][nb] = __builtin_amdgcn_mfma_f32_16x16x32_bf16(cal1, bh, acc[1][nb], 0,0,0);
      }
    }
  }

  int n = lane & 15;
  int xq = x0 + q*4;
  #pragma unroll
  for (int mg=0; mg<2; ++mg){
    int yo = y0 + mg*4;
    if (yo < 100 && xq < 100){
      #pragma unroll
      for (int nb=0; nb<4; ++nb){
        int co = cog*64 + nb*16 + n;
        float s = bns[co], bv = bnb[co];
        floatx4 a = acc[mg][nb];
        float4 v;
        v.x = fmaxf(a[0]*s+bv, 0.f);
        v.y = fmaxf(a[1]*s+bv, 0.f);
        v.z = fmaxf(a[2]*s+bv, 0.f);
        v.w = fmaxf(a[3]*s+bv, 0.f);
        size_t o = ((size_t)(bb*Cout+co)*100 + yo)*100 + xq;
        if (res){
          float4 rv = *(const float4*)(res + o);
          v.x += rv.x; v.y += rv.y; v.z += rv.z; v.w += rv.w;
        }
        *(float4*)(out + o) = v;
      }
    }
  }
}

// ---------- final 1x1 conv 128->16 ----------
__global__ __launch_bounds__(256) void k_final(
    const float* __restrict__ h, const float* __restrict__ W, const float* __restrict__ bias,
    float* __restrict__ out)
{
  int pix = blockIdx.x*256 + threadIdx.x;
  int oc = blockIdx.y, b = blockIdx.z;
  if (pix >= 10000) return;
  const float* hb_ = h + (size_t)b*128*10000 + pix;
  const float* w = W + (size_t)oc*128;
  float acc = bias[oc];
  for (int ci=0; ci<128; ++ci) acc += hb_[(size_t)ci*10000]*w[ci];
  out[((size_t)(b*16+oc))*10000 + pix] = acc;
}

extern "C" void kernel_launch(void* const* d_in, const int* in_sizes, int n_in,
                              void* d_out, int out_size, void* d_ws, size_t ws_size,
                              hipStream_t stream)
{
  (void)in_sizes; (void)n_in; (void)out_size; (void)ws_size;
  const float* feats = (const float*)d_in[0];
  const float* rots  = (const float*)d_in[1];
  const float* trans = (const float*)d_in[2];
  const float* intr  = (const float*)d_in[3];
  const float* nw1   = (const float*)d_in[4];
  const float* bn1s  = (const float*)d_in[5];
  const float* bn1b  = (const float*)d_in[6];
  const float* se1w1 = (const float*)d_in[7];
  const float* se1b1 = (const float*)d_in[8];
  const float* se1w2 = (const float*)d_in[9];
  const float* se1b2 = (const float*)d_in[10];
  const float* nw2   = (const float*)d_in[11];
  const float* bn2s  = (const float*)d_in[12];
  const float* bn2b  = (const float*)d_in[13];
  const float* dhw   = (const float*)d_in[14];
  const float* dhb   = (const float*)d_in[15];
  const float* chw   = (const float*)d_in[16];
  const float* chb   = (const float*)d_in[17];
  const float* bcw1  = (const float*)d_in[18];
  const float* bcs1  = (const float*)d_in[19];
  const float* bcb1  = (const float*)d_in[20];
  const float* bcsw1 = (const float*)d_in[21];
  const float* bcsb1 = (const float*)d_in[22];
  const float* bcsw2 = (const float*)d_in[23];
  const float* bcsb2 = (const float*)d_in[24];
  const float* bcw2  = (const float*)d_in[25];
  const float* bcs2  = (const float*)d_in[26];
  const float* bcb2  = (const float*)d_in[27];
  const float* dw1   = (const float*)d_in[28];
  const float* ds1   = (const float*)d_in[29];
  const float* db1   = (const float*)d_in[30];
  const float* dw2   = (const float*)d_in[31];
  const float* db2   = (const float*)d_in[32];
  float* out = (float*)d_out;

  // ---- workspace layout (float units) ----
  float* ws = (float*)d_ws;
  float* bev   = ws;                       // S0: 5,120,000
  float* h1    = ws + 5120000;             // S1: 5,120,000
  hb*    Ah    = (hb*)(ws + 10240000);     // S2: 2,663,424 fu
  hb*    Al    = (hb*)(ws + 12903424);     // S3: 2,663,424 fu
  float* x2    = ws + 15566848;            // S4: 1,216,512
  float* S5    = ws + 16783360;            // 589,824
  float* dep   = ws + 17373184;            // 190,080
  float* ctx2  = ws + 17563264;            // 304,128
  float* mean1 = ws + 17867392;            // 3072
  float* g1    = mean1 + 3072;
  float* mean2 = g1 + 3072;
  float* g2    = mean2 + 512;
  int*   vox   = (int*)(ws + 17875584);    // 190,080 ints
  // phase aliases
  hb* Fh   = (hb*)bev;                     // 3,041,280 fu
  hb* Wc1h = (hb*)(bev + 3041280);         // 163,840 fu
  hb* Wc1l = (hb*)(bev + 3205120);         // 163,840 fu
  float* x1 = h1;                          // NHWC conv1 out
  hb* Fl   = (hb*)(h1 + 1216512);          // 3,041,280 fu
  hb* Xh   = (hb*)Ah;
  hb* Xl   = (hb*)Al;
  hb* Wc2h = (hb*)S5;                      // 294,912 fu
  hb* Wc2l = (hb*)(S5 + 294912);           // 294,912 fu
  int* cnt  = (int*)h1;
  int* off  = cnt + 80000;
  int* cur  = off + 80000;
  int* bsum = cur + 80000;
  int* list = bsum + 1024;
  float* h3 = h1;
  hb* Wp1h = (hb*)x2;
  hb* Wp1l = (hb*)(x2 + 294912);
  hb* Wp3h = (hb*)(x2 + 589824);
  hb* Wp3l = (hb*)(x2 + 589824 + 147456);
  hb* Wp2h = (hb*)S5;
  hb* Wp2l = (hb*)(S5 + 294912);

  // ---- image branch (MFMA) ----
  k_trans_feats<<<dim3(7,20,12),256,0,stream>>>(feats,Fh,Fl);
  k_wpack1<<<1280,256,0,stream>>>(nw1,Wc1h,Wc1l);
  k_mfma_gemm1<<<dim3(38,4),256,0,stream>>>(Fh,Fl,Wc1h,Wc1l,bn1s,bn1b,x1);
  k_meanN<<<12,256,0,stream>>>(x1,mean1);
  k_se_fc<<<12,256,0,stream>>>(mean1,se1w1,se1b1,se1w2,se1b2,g1,32);
  k_topad<<<dim3(14,12),256,0,stream>>>(x1,g1,Xh,Xl);
  k_wpack<<<(589824+255)/256,256,0,stream>>>(nw2,Wc2h,Wc2l,16);
  k_conv3s_mfma<<<dim3(38,4),256,0,stream>>>(Xh,Xl,Wc2h,Wc2l,bn2s,bn2b,x2);
  k_heads<<<dim3(2,104,12),256,0,stream>>>(x2,dhw,dhb,chw,chb,dep,ctx2);
  k_softmax40<<<(4752+255)/256,256,0,stream>>>(dep);

  // ---- pack BEV conv weights kb-major ----
  k_wpackT<<<(589824+255)/256,256,0,stream>>>(bcw1,Wp1h,Wp1l,16);
  k_wpackT<<<(589824+255)/256,256,0,stream>>>(bcw2,Wp2h,Wp2l,16);
  k_wpackT<<<(294912+255)/256,256,0,stream>>>(dw1,Wp3h,Wp3l,8);

  // ---- lift-splat (gather form) ----
  hipMemsetAsync(cnt, 0, 80000*sizeof(int), stream);
  k_geom<<<(190080+255)/256,256,0,stream>>>(rots,trans,intr,vox,cnt);
  k_scan1<<<313,256,0,stream>>>(cnt,off,bsum);
  k_scan2<<<1,64,0,stream>>>(bsum,313);
  k_scan3<<<(80000+255)/256,256,0,stream>>>(off,bsum,cur);
  k_fill<<<(190080+255)/256,256,0,stream>>>(vox,cur,list);
  k_gather<<<20000,256,0,stream>>>(off,cnt,list,ctx2,dep,bev);

  // ---- BEV encoder (MFMA convs, LDS-staged) ----
  k_tohwc2<<<dim3(102,2,8),256,0,stream>>>(bev,Ah,Al,nullptr);
  k_conv3_bevm<<<728,256,0,stream>>>(Ah,Al,Wp1h,Wp1l,bcs1,bcb1,nullptr,h1,256,4);
  k_rowmean<<<512,256,0,stream>>>(h1,mean2,10000,1e-4f);
  k_se_fc<<<2,256,0,stream>>>(mean2,bcsw1,bcsb1,bcsw2,bcsb2,g2,16);
  k_tohwc2<<<dim3(102,2,8),256,0,stream>>>(h1,Ah,Al,g2);
  k_conv3_bevm<<<728,256,0,stream>>>(Ah,Al,Wp2h,Wp2l,bcs2,bcb2,bev,bev,256,4);
  k_tohwc2<<<dim3(102,2,8),256,0,stream>>>(bev,Ah,Al,nullptr);
  k_conv3_bevm<<<364,256,0,stream>>>(Ah,Al,Wp3h,Wp3l,ds1,db1,nullptr,h3,128,2);
  k_final<<<dim3(40,16,2),256,0,stream>>>(h3,dw2,db2,out);
}